// Round 1
// baseline (813.371 us; speedup 1.0000x reference)
//
#include <hip/hip_runtime.h>
#include <stdint.h>

#define NN 12288
#define IND 512
#define H1D 256
#define H2D 128

using bf16x8 = __attribute__((ext_vector_type(8))) short;
using f32x4  = __attribute__((ext_vector_type(4))) float;

__device__ __forceinline__ unsigned short f2bf(float f){
  unsigned int u = __float_as_uint(f);
  return (unsigned short)((u + 0x7fffu + ((u >> 16) & 1u)) >> 16);
}
__device__ __forceinline__ float bf2f(unsigned short h){
  return __uint_as_float(((unsigned int)h) << 16);
}
__device__ __forceinline__ void gload_lds16(const void* g, void* l){
  __builtin_amdgcn_global_load_lds(
      (const __attribute__((address_space(1))) unsigned int*)(uintptr_t)g,
      (__attribute__((address_space(3))) unsigned int*)(unsigned int)(uintptr_t)l,
      16, 0, 0);
}

// ---------------- Kernel 1: XW0T[h1][n] = bf16( (X @ W0)[n][h1] ) ----------------
__global__ __launch_bounds__(256) void k_xw0(const float* __restrict__ X,
                                             const float* __restrict__ W0,
                                             unsigned short* __restrict__ XW0T){
  __shared__ float XsT[32][68];   // [k][n], padded, 16B-aligned rows (68*4=272=17*16)
  __shared__ float Ws[32][36];    // [k][h1]
  const int t  = (int)threadIdx.x;
  const int n0 = (int)blockIdx.x * 64;
  const int h0 = (int)blockIdx.y * 32;
  const int xr = t >> 2, xc = (t & 3) * 8;
  const int h  = t >> 3, ng = t & 7;
  float acc[8];
#pragma unroll
  for (int j = 0; j < 8; ++j) acc[j] = 0.f;

  for (int k0 = 0; k0 < IND; k0 += 32){
    {
      const float* xp = X + (size_t)(n0 + xr) * IND + k0 + xc;
      float4 a = *(const float4*)xp;
      float4 b = *(const float4*)(xp + 4);
      XsT[xc+0][xr]=a.x; XsT[xc+1][xr]=a.y; XsT[xc+2][xr]=a.z; XsT[xc+3][xr]=a.w;
      XsT[xc+4][xr]=b.x; XsT[xc+5][xr]=b.y; XsT[xc+6][xr]=b.z; XsT[xc+7][xr]=b.w;
    }
    if (t < 128){
      const float* wp = W0 + (size_t)(k0 + xr) * H1D + h0 + xc;
      float4 a = *(const float4*)wp;
      float4 b = *(const float4*)(wp + 4);
      Ws[xr][xc+0]=a.x; Ws[xr][xc+1]=a.y; Ws[xr][xc+2]=a.z; Ws[xr][xc+3]=a.w;
      Ws[xr][xc+4]=b.x; Ws[xr][xc+5]=b.y; Ws[xr][xc+6]=b.z; Ws[xr][xc+7]=b.w;
    }
    __syncthreads();
#pragma unroll 8
    for (int kk = 0; kk < 32; ++kk){
      float wv = Ws[kk][h];
      const float4 x0 = *(const float4*)&XsT[kk][ng*8];
      const float4 x1 = *(const float4*)&XsT[kk][ng*8+4];
      acc[0] += x0.x*wv; acc[1] += x0.y*wv; acc[2] += x0.z*wv; acc[3] += x0.w*wv;
      acc[4] += x1.x*wv; acc[5] += x1.y*wv; acc[6] += x1.z*wv; acc[7] += x1.w*wv;
    }
    __syncthreads();
  }
  uint4 pk;
  pk.x = (unsigned)f2bf(acc[0]) | ((unsigned)f2bf(acc[1]) << 16);
  pk.y = (unsigned)f2bf(acc[2]) | ((unsigned)f2bf(acc[3]) << 16);
  pk.z = (unsigned)f2bf(acc[4]) | ((unsigned)f2bf(acc[5]) << 16);
  pk.w = (unsigned)f2bf(acc[6]) | ((unsigned)f2bf(acc[7]) << 16);
  *(uint4*)(XW0T + (size_t)(h0 + h) * NN + n0 + ng*8) = pk;
}

// ------------- Kernel 2/3: C[12288 x 256] = adj(f32) @ B, B given transposed bf16 -------------
// MODE 0: store relu(C)^T as bf16 into Out ([256][12288])  (hiddenT)
// MODE 1: store C as f32 into Out ([12288][256])           (AH)
template<int MODE>
__global__ __launch_bounds__(512) void k_gemm_adj(const float* __restrict__ A,
                                                  const unsigned short* __restrict__ Bt,
                                                  void* __restrict__ Out){
  __shared__ unsigned short Alds[2][48*64];    // swizzled [row][64k], 128B rows
  __shared__ unsigned short Blds[2][256*64];   // swizzled [col][64k], 128B rows
  const int t = (int)threadIdx.x;
  const int w = t >> 6, l = t & 63;
  const int l15 = l & 15, l16 = l >> 4;
  const int m0 = (int)blockIdx.x * 48;

  f32x4 acc[3][2];
#pragma unroll
  for (int mi = 0; mi < 3; ++mi)
#pragma unroll
    for (int ni = 0; ni < 2; ++ni) acc[mi][ni] = 0;

  const int ar = t >> 3, ac8 = (t & 7) * 8;
  const bool astage = (t < 384);
  const float* abase = A + (size_t)(m0 + ar) * NN + ac8;
  const int aoff = ar*128 + ((ac8*2) ^ ((ar & 7) << 4));

  // prologue: stage step 0
  if (astage){
    float4 v0 = *(const float4*)(abase);
    float4 v1 = *(const float4*)(abase + 4);
    uint4 pk;
    pk.x = (unsigned)f2bf(v0.x) | ((unsigned)f2bf(v0.y) << 16);
    pk.y = (unsigned)f2bf(v0.z) | ((unsigned)f2bf(v0.w) << 16);
    pk.z = (unsigned)f2bf(v1.x) | ((unsigned)f2bf(v1.y) << 16);
    pk.w = (unsigned)f2bf(v1.z) | ((unsigned)f2bf(v1.w) << 16);
    *(uint4*)((char*)Alds[0] + aoff) = pk;
  }
#pragma unroll
  for (int i = 0; i < 4; ++i){
    int P = i*8192 + t*16;
    int row = P >> 7;
    int Li = (P & 127) ^ ((row & 7) << 4);
    gload_lds16((const char*)Bt + (size_t)row * (NN*2) + Li,
                (char*)Blds[0] + i*8192 + w*1024);
  }
  __syncthreads();

  for (int s = 0; s < 192; ++s){
    const int cur = s & 1, nxt = cur ^ 1;
    float4 v0, v1;
    if (s + 1 < 192){
      if (astage){
        v0 = *(const float4*)(abase + (size_t)(s+1)*64);
        v1 = *(const float4*)(abase + (size_t)(s+1)*64 + 4);
      }
#pragma unroll
      for (int i = 0; i < 4; ++i){
        int P = i*8192 + t*16;
        int row = P >> 7;
        int Li = (P & 127) ^ ((row & 7) << 4);
        gload_lds16((const char*)Bt + (size_t)row * (NN*2) + (size_t)(s+1)*128 + Li,
                    (char*)Blds[nxt] + i*8192 + w*1024);
      }
    }
#pragma unroll
    for (int kk = 0; kk < 2; ++kk){
      bf16x8 af[3], bfr[2];
#pragma unroll
      for (int mi = 0; mi < 3; ++mi){
        int row = mi*16 + l15;
        int off = row*128 + ((kk*64 + l16*16) ^ ((row & 7) << 4));
        af[mi] = *(const bf16x8*)((const char*)Alds[cur] + off);
      }
#pragma unroll
      for (int ni = 0; ni < 2; ++ni){
        int row = w*32 + ni*16 + l15;
        int off = row*128 + ((kk*64 + l16*16) ^ ((row & 7) << 4));
        bfr[ni] = *(const bf16x8*)((const char*)Blds[cur] + off);
      }
#pragma unroll
      for (int mi = 0; mi < 3; ++mi)
#pragma unroll
        for (int ni = 0; ni < 2; ++ni)
          acc[mi][ni] = __builtin_amdgcn_mfma_f32_16x16x32_bf16(af[mi], bfr[ni], acc[mi][ni], 0, 0, 0);
    }
    if (s + 1 < 192 && astage){
      uint4 pk;
      pk.x = (unsigned)f2bf(v0.x) | ((unsigned)f2bf(v0.y) << 16);
      pk.y = (unsigned)f2bf(v0.z) | ((unsigned)f2bf(v0.w) << 16);
      pk.z = (unsigned)f2bf(v1.x) | ((unsigned)f2bf(v1.y) << 16);
      pk.w = (unsigned)f2bf(v1.z) | ((unsigned)f2bf(v1.w) << 16);
      *(uint4*)((char*)Alds[nxt] + aoff) = pk;
    }
    __syncthreads();
  }

  if (MODE == 0){
    unsigned short* HT = (unsigned short*)Out;
#pragma unroll
    for (int mi = 0; mi < 3; ++mi)
#pragma unroll
      for (int ni = 0; ni < 2; ++ni){
        int gr = m0 + mi*16 + l16*4;
        int gc = w*32 + ni*16 + l15;
        unsigned short h0 = f2bf(fmaxf(acc[mi][ni][0], 0.f));
        unsigned short h1 = f2bf(fmaxf(acc[mi][ni][1], 0.f));
        unsigned short h2 = f2bf(fmaxf(acc[mi][ni][2], 0.f));
        unsigned short h3 = f2bf(fmaxf(acc[mi][ni][3], 0.f));
        uint2 pk;
        pk.x = (unsigned)h0 | ((unsigned)h1 << 16);
        pk.y = (unsigned)h2 | ((unsigned)h3 << 16);
        *(uint2*)(HT + (size_t)gc * NN + gr) = pk;
      }
  } else {
    float* AHp = (float*)Out;
#pragma unroll
    for (int mi = 0; mi < 3; ++mi)
#pragma unroll
      for (int ni = 0; ni < 2; ++ni){
        int gr = m0 + mi*16 + l16*4;
        int gc = w*32 + ni*16 + l15;
#pragma unroll
        for (int v = 0; v < 4; ++v)
          AHp[(size_t)(gr + v) * H1D + gc] = acc[mi][ni][v];
      }
  }
}

// ---------------- Kernel 4: heads + reparameterization -> Zhi/Zlo (split bf16) ----------------
__global__ __launch_bounds__(256) void k_heads(const float* __restrict__ AH,
                                               const float* __restrict__ Wmu,
                                               const float* __restrict__ Wls,
                                               const float* __restrict__ noise,
                                               unsigned short* __restrict__ Zhi,
                                               unsigned short* __restrict__ Zlo){
  __shared__ float AHs[32][256];
  __shared__ float Wms[32][128];
  __shared__ float Wlss[32][128];
  const int t  = (int)threadIdx.x;
  const int r0 = (int)blockIdx.x * 32;
  {
    const int r = t >> 3, c0 = (t & 7) * 32;
    const float* p = AH + (size_t)(r0 + r) * H1D + c0;
#pragma unroll
    for (int q = 0; q < 8; ++q)
      *(float4*)&AHs[r][c0 + q*4] = *(const float4*)(p + q*4);
  }
  const int j = t & 127, rg = t >> 7;
  float mu[16], ls[16];
#pragma unroll
  for (int r = 0; r < 16; ++r){ mu[r] = 0.f; ls[r] = 0.f; }

  for (int kc = 0; kc < 8; ++kc){
    __syncthreads();
    {
      const int r = t >> 3, c0 = (t & 7) * 16;
      const float* pm = Wmu + (size_t)(kc*32 + r) * H2D + c0;
      const float* pl = Wls + (size_t)(kc*32 + r) * H2D + c0;
#pragma unroll
      for (int q = 0; q < 4; ++q){
        *(float4*)&Wms[r][c0 + q*4]  = *(const float4*)(pm + q*4);
        *(float4*)&Wlss[r][c0 + q*4] = *(const float4*)(pl + q*4);
      }
    }
    __syncthreads();
#pragma unroll 4
    for (int k = 0; k < 32; ++k){
      float wm = Wms[k][j], wl = Wlss[k][j];
#pragma unroll
      for (int r = 0; r < 16; ++r){
        float a = AHs[rg*16 + r][kc*32 + k];
        mu[r] += a * wm;
        ls[r] += a * wl;
      }
    }
  }
#pragma unroll
  for (int r = 0; r < 16; ++r){
    const int i = r0 + rg*16 + r;
    float z = noise[(size_t)i * H2D + j] * __expf(ls[r]) + mu[r];
    unsigned short zh = f2bf(z);
    unsigned short zl = f2bf(z - bf2f(zh));
    Zhi[(size_t)i * H2D + j] = zh;
    Zlo[(size_t)i * H2D + j] = zl;
  }
}

// ---------------- Kernel 5: A_pred = sigmoid(Z @ Z^T), split-bf16 ----------------
__global__ __launch_bounds__(512) void k_decode(const unsigned short* __restrict__ Zhi,
                                                const unsigned short* __restrict__ Zlo,
                                                float* __restrict__ Out){
  __shared__ unsigned short T[4][128*64];   // Ahi, Alo, Bhi, Blo : 16KB each, swizzled 128B rows
  const int t = (int)threadIdx.x;
  const int w = t >> 6, l = t & 63;
  const int l15 = l & 15, l16 = l >> 4;
  const int wr = w >> 2, wc = w & 3;
  const size_t m0 = (size_t)blockIdx.x * 128;
  const size_t n0 = (size_t)blockIdx.y * 128;

  f32x4 acc[4][2];
#pragma unroll
  for (int mi = 0; mi < 4; ++mi)
#pragma unroll
    for (int ni = 0; ni < 2; ++ni) acc[mi][ni] = 0;

#pragma unroll
  for (int p = 0; p < 2; ++p){
    if (p) __syncthreads();
#pragma unroll
    for (int i = 0; i < 2; ++i){
      int P = i*8192 + t*16;
      int row = P >> 7;
      int Li = (P & 127) ^ ((row & 7) << 4);
      size_t ga = (size_t)row * 256 + (size_t)p * 128 + Li;
      char* lb0 = (char*)T[0] + i*8192 + w*1024;
      char* lb1 = (char*)T[1] + i*8192 + w*1024;
      char* lb2 = (char*)T[2] + i*8192 + w*1024;
      char* lb3 = (char*)T[3] + i*8192 + w*1024;
      gload_lds16((const char*)Zhi + m0*256 + ga, lb0);
      gload_lds16((const char*)Zlo + m0*256 + ga, lb1);
      gload_lds16((const char*)Zhi + n0*256 + ga, lb2);
      gload_lds16((const char*)Zlo + n0*256 + ga, lb3);
    }
    __syncthreads();
#pragma unroll
    for (int kk = 0; kk < 2; ++kk){
      bf16x8 ah[4], al[4], bh[2], bl[2];
#pragma unroll
      for (int mi = 0; mi < 4; ++mi){
        int row = wr*64 + mi*16 + l15;
        int off = row*128 + ((kk*64 + l16*16) ^ ((row & 7) << 4));
        ah[mi] = *(const bf16x8*)((const char*)T[0] + off);
        al[mi] = *(const bf16x8*)((const char*)T[1] + off);
      }
#pragma unroll
      for (int ni = 0; ni < 2; ++ni){
        int row = wc*32 + ni*16 + l15;
        int off = row*128 + ((kk*64 + l16*16) ^ ((row & 7) << 4));
        bh[ni] = *(const bf16x8*)((const char*)T[2] + off);
        bl[ni] = *(const bf16x8*)((const char*)T[3] + off);
      }
#pragma unroll
      for (int mi = 0; mi < 4; ++mi)
#pragma unroll
        for (int ni = 0; ni < 2; ++ni){
          acc[mi][ni] = __builtin_amdgcn_mfma_f32_16x16x32_bf16(ah[mi], bh[ni], acc[mi][ni], 0, 0, 0);
          acc[mi][ni] = __builtin_amdgcn_mfma_f32_16x16x32_bf16(ah[mi], bl[ni], acc[mi][ni], 0, 0, 0);
          acc[mi][ni] = __builtin_amdgcn_mfma_f32_16x16x32_bf16(al[mi], bh[ni], acc[mi][ni], 0, 0, 0);
        }
    }
  }

#pragma unroll
  for (int mi = 0; mi < 4; ++mi)
#pragma unroll
    for (int ni = 0; ni < 2; ++ni){
      size_t gr = m0 + (size_t)(wr*64 + mi*16 + l16*4);
      size_t gc = n0 + (size_t)(wc*32 + ni*16 + l15);
#pragma unroll
      for (int v = 0; v < 4; ++v){
        float x = acc[mi][ni][v];
        Out[(gr + v) * (size_t)NN + gc] = 1.0f / (1.0f + __expf(-x));
      }
    }
}

extern "C" void kernel_launch(void* const* d_in, const int* in_sizes, int n_in,
                              void* d_out, int out_size, void* d_ws, size_t ws_size,
                              hipStream_t stream) {
  const float* X     = (const float*)d_in[0];
  const float* adj   = (const float*)d_in[1];
  const float* noise = (const float*)d_in[2];
  const float* W0    = (const float*)d_in[3];
  const float* Wmu   = (const float*)d_in[4];
  const float* Wls   = (const float*)d_in[5];
  float* out = (float*)d_out;
  char* ws = (char*)d_ws;

  unsigned short* XW0T = (unsigned short*)(ws);                 // 256*12288*2 = 6291456
  unsigned short* HT   = (unsigned short*)(ws + 6291456);       // 6291456
  float*          AH   = (float*)(ws + 12582912);               // 12288*256*4 = 12582912
  unsigned short* Zhi  = (unsigned short*)(ws + 25165824);      // 3145728
  unsigned short* Zlo  = (unsigned short*)(ws + 28311552);      // 3145728

  k_xw0<<<dim3(192, 8), 256, 0, stream>>>(X, W0, XW0T);
  k_gemm_adj<0><<<256, 512, 0, stream>>>(adj, XW0T, (void*)HT);
  k_gemm_adj<1><<<256, 512, 0, stream>>>(adj, HT, (void*)AH);
  k_heads<<<384, 256, 0, stream>>>(AH, Wmu, Wls, noise, Zhi, Zlo);
  k_decode<<<dim3(96, 96), 512, 0, stream>>>(Zhi, Zlo, out);
}

// Round 2
// 723.160 us; speedup vs baseline: 1.1247x; 1.1247x over previous
//
#include <hip/hip_runtime.h>
#include <stdint.h>

#define NN 12288
#define IND 512
#define H1D 256
#define H2D 128

using bf16x8 = __attribute__((ext_vector_type(8))) short;
using f32x4  = __attribute__((ext_vector_type(4))) float;

__device__ __forceinline__ unsigned short f2bf(float f){
  unsigned int u = __float_as_uint(f);
  return (unsigned short)((u + 0x7fffu + ((u >> 16) & 1u)) >> 16);
}
__device__ __forceinline__ float bf2f(unsigned short h){
  return __uint_as_float(((unsigned int)h) << 16);
}
__device__ __forceinline__ void gload_lds16(const void* g, void* l){
  __builtin_amdgcn_global_load_lds(
      (const __attribute__((address_space(1))) unsigned int*)(uintptr_t)g,
      (__attribute__((address_space(3))) unsigned int*)(unsigned int)(uintptr_t)l,
      16, 0, 0);
}

// ---------------- Kernel 1: XW0T[h1][n] = bf16( (X @ W0)[n][h1] ) ----------------
__global__ __launch_bounds__(256) void k_xw0(const float* __restrict__ X,
                                             const float* __restrict__ W0,
                                             unsigned short* __restrict__ XW0T){
  __shared__ float XsT[32][68];
  __shared__ float Ws[32][36];
  const int t  = (int)threadIdx.x;
  const int n0 = (int)blockIdx.x * 64;
  const int h0 = (int)blockIdx.y * 32;
  const int xr = t >> 2, xc = (t & 3) * 8;
  const int h  = t >> 3, ng = t & 7;
  float acc[8];
#pragma unroll
  for (int j = 0; j < 8; ++j) acc[j] = 0.f;

  for (int k0 = 0; k0 < IND; k0 += 32){
    {
      const float* xp = X + (size_t)(n0 + xr) * IND + k0 + xc;
      float4 a = *(const float4*)xp;
      float4 b = *(const float4*)(xp + 4);
      XsT[xc+0][xr]=a.x; XsT[xc+1][xr]=a.y; XsT[xc+2][xr]=a.z; XsT[xc+3][xr]=a.w;
      XsT[xc+4][xr]=b.x; XsT[xc+5][xr]=b.y; XsT[xc+6][xr]=b.z; XsT[xc+7][xr]=b.w;
    }
    if (t < 128){
      const float* wp = W0 + (size_t)(k0 + xr) * H1D + h0 + xc;
      float4 a = *(const float4*)wp;
      float4 b = *(const float4*)(wp + 4);
      Ws[xr][xc+0]=a.x; Ws[xr][xc+1]=a.y; Ws[xr][xc+2]=a.z; Ws[xr][xc+3]=a.w;
      Ws[xr][xc+4]=b.x; Ws[xr][xc+5]=b.y; Ws[xr][xc+6]=b.z; Ws[xr][xc+7]=b.w;
    }
    __syncthreads();
#pragma unroll 8
    for (int kk = 0; kk < 32; ++kk){
      float wv = Ws[kk][h];
      const float4 x0 = *(const float4*)&XsT[kk][ng*8];
      const float4 x1 = *(const float4*)&XsT[kk][ng*8+4];
      acc[0] += x0.x*wv; acc[1] += x0.y*wv; acc[2] += x0.z*wv; acc[3] += x0.w*wv;
      acc[4] += x1.x*wv; acc[5] += x1.y*wv; acc[6] += x1.z*wv; acc[7] += x1.w*wv;
    }
    __syncthreads();
  }
  uint4 pk;
  pk.x = (unsigned)f2bf(acc[0]) | ((unsigned)f2bf(acc[1]) << 16);
  pk.y = (unsigned)f2bf(acc[2]) | ((unsigned)f2bf(acc[3]) << 16);
  pk.z = (unsigned)f2bf(acc[4]) | ((unsigned)f2bf(acc[5]) << 16);
  pk.w = (unsigned)f2bf(acc[6]) | ((unsigned)f2bf(acc[7]) << 16);
  *(uint4*)(XW0T + (size_t)(h0 + h) * NN + n0 + ng*8) = pk;
}

// ------------- Kernel 2/3: split-K adj GEMM: part[khalf] = adj[:, khalf] @ B[khalf, :] -------------
// A: adj f32 [12288][12288]; Bt: [256][12288] bf16 (k-contiguous rows); part: [2][12288][256] f32
__global__ __launch_bounds__(512, 4) void k_gemm_adj(const float* __restrict__ A,
                                                     const unsigned short* __restrict__ Bt,
                                                     float* __restrict__ part){
  __shared__ unsigned short Alds[2][48*64];    // swizzled, 128B rows
  __shared__ unsigned short Blds[2][256*64];   // swizzled, 128B rows
  const int t = (int)threadIdx.x;
  const int w = t >> 6, l = t & 63;
  const int l15 = l & 15, l16 = l >> 4;
  const int m0 = (int)blockIdx.x * 48;
  const int khalf = (int)blockIdx.y;
  const int kbase = khalf * 6144;              // elements
  const size_t kbyte = (size_t)kbase * 2;      // bytes into Bt rows

  f32x4 acc[3][2];
#pragma unroll
  for (int mi = 0; mi < 3; ++mi)
#pragma unroll
    for (int ni = 0; ni < 2; ++ni) acc[mi][ni] = 0;

  const int ar = t >> 3, ac8 = (t & 7) * 8;
  const bool astage = (t < 384);
  const float* abase = A + (size_t)(m0 + ar) * NN + kbase + ac8;
  const int aoff = ar*128 + ((ac8*2) ^ ((ar & 7) << 4));

  if (astage){
    float4 v0 = *(const float4*)(abase);
    float4 v1 = *(const float4*)(abase + 4);
    uint4 pk;
    pk.x = (unsigned)f2bf(v0.x) | ((unsigned)f2bf(v0.y) << 16);
    pk.y = (unsigned)f2bf(v0.z) | ((unsigned)f2bf(v0.w) << 16);
    pk.z = (unsigned)f2bf(v1.x) | ((unsigned)f2bf(v1.y) << 16);
    pk.w = (unsigned)f2bf(v1.z) | ((unsigned)f2bf(v1.w) << 16);
    *(uint4*)((char*)Alds[0] + aoff) = pk;
  }
#pragma unroll
  for (int i = 0; i < 4; ++i){
    int P = i*8192 + t*16;
    int row = P >> 7;
    int Li = (P & 127) ^ ((row & 7) << 4);
    gload_lds16((const char*)Bt + (size_t)row * (NN*2) + kbyte + Li,
                (char*)Blds[0] + i*8192 + w*1024);
  }
  __syncthreads();

  for (int s = 0; s < 96; ++s){
    const int cur = s & 1, nxt = cur ^ 1;
    float4 v0, v1;
    if (s + 1 < 96){
      if (astage){
        v0 = *(const float4*)(abase + (size_t)(s+1)*64);
        v1 = *(const float4*)(abase + (size_t)(s+1)*64 + 4);
      }
#pragma unroll
      for (int i = 0; i < 4; ++i){
        int P = i*8192 + t*16;
        int row = P >> 7;
        int Li = (P & 127) ^ ((row & 7) << 4);
        gload_lds16((const char*)Bt + (size_t)row * (NN*2) + kbyte + (size_t)(s+1)*128 + Li,
                    (char*)Blds[nxt] + i*8192 + w*1024);
      }
    }
#pragma unroll
    for (int kk = 0; kk < 2; ++kk){
      bf16x8 af[3], bfr[2];
#pragma unroll
      for (int mi = 0; mi < 3; ++mi){
        int row = mi*16 + l15;
        int off = row*128 + ((kk*64 + l16*16) ^ ((row & 7) << 4));
        af[mi] = *(const bf16x8*)((const char*)Alds[cur] + off);
      }
#pragma unroll
      for (int ni = 0; ni < 2; ++ni){
        int row = w*32 + ni*16 + l15;
        int off = row*128 + ((kk*64 + l16*16) ^ ((row & 7) << 4));
        bfr[ni] = *(const bf16x8*)((const char*)Blds[cur] + off);
      }
#pragma unroll
      for (int mi = 0; mi < 3; ++mi)
#pragma unroll
        for (int ni = 0; ni < 2; ++ni)
          acc[mi][ni] = __builtin_amdgcn_mfma_f32_16x16x32_bf16(af[mi], bfr[ni], acc[mi][ni], 0, 0, 0);
    }
    if (s + 1 < 96 && astage){
      uint4 pk;
      pk.x = (unsigned)f2bf(v0.x) | ((unsigned)f2bf(v0.y) << 16);
      pk.y = (unsigned)f2bf(v0.z) | ((unsigned)f2bf(v0.w) << 16);
      pk.z = (unsigned)f2bf(v1.x) | ((unsigned)f2bf(v1.y) << 16);
      pk.w = (unsigned)f2bf(v1.z) | ((unsigned)f2bf(v1.w) << 16);
      *(uint4*)((char*)Alds[nxt] + aoff) = pk;
    }
    __syncthreads();
  }

  float* P = part + (size_t)khalf * NN * H1D;
#pragma unroll
  for (int mi = 0; mi < 3; ++mi)
#pragma unroll
    for (int ni = 0; ni < 2; ++ni){
      int gr = m0 + mi*16 + l16*4;
      int gc = w*32 + ni*16 + l15;
#pragma unroll
      for (int v = 0; v < 4; ++v)
        P[(size_t)(gr + v) * H1D + gc] = acc[mi][ni][v];
    }
}

// ---------------- combine GEMM1 partials -> HT[h][n] = bf16(relu(p0+p1)) (transposed) ----------------
__global__ __launch_bounds__(256) void k_combine_ht(const float* __restrict__ p0,
                                                    const float* __restrict__ p1,
                                                    unsigned short* __restrict__ HT){
  __shared__ float Ls[64][65];
  const int t = (int)threadIdx.x;
  const int n0 = (int)blockIdx.x * 64;
  const int h0 = (int)blockIdx.y * 64;
  const int lr = t >> 4, lc = (t & 15) * 4;
#pragma unroll
  for (int q = 0; q < 4; ++q){
    int n = lr + q*16;
    size_t idx = (size_t)(n0 + n) * H1D + h0 + lc;
    float4 a = *(const float4*)(p0 + idx);
    float4 b = *(const float4*)(p1 + idx);
    Ls[n][lc+0] = fmaxf(a.x + b.x, 0.f);
    Ls[n][lc+1] = fmaxf(a.y + b.y, 0.f);
    Ls[n][lc+2] = fmaxf(a.z + b.z, 0.f);
    Ls[n][lc+3] = fmaxf(a.w + b.w, 0.f);
  }
  __syncthreads();
  const int hr = t >> 2, nc = (t & 3) * 16;
  unsigned int pk[8];
#pragma unroll
  for (int q = 0; q < 8; ++q){
    float x0 = Ls[nc + q*2 + 0][hr];
    float x1 = Ls[nc + q*2 + 1][hr];
    pk[q] = (unsigned)f2bf(x0) | ((unsigned)f2bf(x1) << 16);
  }
  unsigned short* dst = HT + (size_t)(h0 + hr) * NN + n0 + nc;
  *(uint4*)(dst)     = *(uint4*)&pk[0];
  *(uint4*)(dst + 8) = *(uint4*)&pk[4];
}

// ---------------- Kernel 4: heads (reads GEMM2 partials) + reparam -> Zhi/Zlo ----------------
__global__ __launch_bounds__(256) void k_heads(const float* __restrict__ p0,
                                               const float* __restrict__ Wmu,
                                               const float* __restrict__ Wls,
                                               const float* __restrict__ noise,
                                               unsigned short* __restrict__ Zhi,
                                               unsigned short* __restrict__ Zlo){
  __shared__ float AHs[32][256];
  __shared__ float Wms[32][128];
  __shared__ float Wlss[32][128];
  const float* p1 = p0 + (size_t)NN * H1D;
  const int t  = (int)threadIdx.x;
  const int r0 = (int)blockIdx.x * 32;
  {
    const int r = t >> 3, c0 = (t & 7) * 32;
    size_t base = (size_t)(r0 + r) * H1D + c0;
#pragma unroll
    for (int q = 0; q < 8; ++q){
      float4 a = *(const float4*)(p0 + base + q*4);
      float4 b = *(const float4*)(p1 + base + q*4);
      AHs[r][c0 + q*4 + 0] = a.x + b.x;
      AHs[r][c0 + q*4 + 1] = a.y + b.y;
      AHs[r][c0 + q*4 + 2] = a.z + b.z;
      AHs[r][c0 + q*4 + 3] = a.w + b.w;
    }
  }
  const int j = t & 127, rg = t >> 7;
  float mu[16], ls[16];
#pragma unroll
  for (int r = 0; r < 16; ++r){ mu[r] = 0.f; ls[r] = 0.f; }

  for (int kc = 0; kc < 8; ++kc){
    __syncthreads();
    {
      const int r = t >> 3, c0 = (t & 7) * 16;
      const float* pm = Wmu + (size_t)(kc*32 + r) * H2D + c0;
      const float* pl = Wls + (size_t)(kc*32 + r) * H2D + c0;
#pragma unroll
      for (int q = 0; q < 4; ++q){
        *(float4*)&Wms[r][c0 + q*4]  = *(const float4*)(pm + q*4);
        *(float4*)&Wlss[r][c0 + q*4] = *(const float4*)(pl + q*4);
      }
    }
    __syncthreads();
#pragma unroll 4
    for (int k = 0; k < 32; ++k){
      float wm = Wms[k][j], wl = Wlss[k][j];
#pragma unroll
      for (int r = 0; r < 16; ++r){
        float a = AHs[rg*16 + r][kc*32 + k];
        mu[r] += a * wm;
        ls[r] += a * wl;
      }
    }
  }
#pragma unroll
  for (int r = 0; r < 16; ++r){
    const int i = r0 + rg*16 + r;
    float z = noise[(size_t)i * H2D + j] * __expf(ls[r]) + mu[r];
    unsigned short zh = f2bf(z);
    unsigned short zl = f2bf(z - bf2f(zh));
    Zhi[(size_t)i * H2D + j] = zh;
    Zlo[(size_t)i * H2D + j] = zl;
  }
}

// ---------------- Kernel 5: A_pred = sigmoid(Z @ Z^T), split-bf16 ----------------
__global__ __launch_bounds__(512) void k_decode(const unsigned short* __restrict__ Zhi,
                                                const unsigned short* __restrict__ Zlo,
                                                float* __restrict__ Out){
  __shared__ unsigned short T[4][128*64];
  const int t = (int)threadIdx.x;
  const int w = t >> 6, l = t & 63;
  const int l15 = l & 15, l16 = l >> 4;
  const int wr = w >> 2, wc = w & 3;
  const size_t m0 = (size_t)blockIdx.x * 128;
  const size_t n0 = (size_t)blockIdx.y * 128;

  f32x4 acc[4][2];
#pragma unroll
  for (int mi = 0; mi < 4; ++mi)
#pragma unroll
    for (int ni = 0; ni < 2; ++ni) acc[mi][ni] = 0;

#pragma unroll
  for (int p = 0; p < 2; ++p){
    if (p) __syncthreads();
#pragma unroll
    for (int i = 0; i < 2; ++i){
      int P = i*8192 + t*16;
      int row = P >> 7;
      int Li = (P & 127) ^ ((row & 7) << 4);
      size_t ga = (size_t)row * 256 + (size_t)p * 128 + Li;
      char* lb0 = (char*)T[0] + i*8192 + w*1024;
      char* lb1 = (char*)T[1] + i*8192 + w*1024;
      char* lb2 = (char*)T[2] + i*8192 + w*1024;
      char* lb3 = (char*)T[3] + i*8192 + w*1024;
      gload_lds16((const char*)Zhi + m0*256 + ga, lb0);
      gload_lds16((const char*)Zlo + m0*256 + ga, lb1);
      gload_lds16((const char*)Zhi + n0*256 + ga, lb2);
      gload_lds16((const char*)Zlo + n0*256 + ga, lb3);
    }
    __syncthreads();
#pragma unroll
    for (int kk = 0; kk < 2; ++kk){
      bf16x8 ah[4], al[4], bh[2], bl[2];
#pragma unroll
      for (int mi = 0; mi < 4; ++mi){
        int row = wr*64 + mi*16 + l15;
        int off = row*128 + ((kk*64 + l16*16) ^ ((row & 7) << 4));
        ah[mi] = *(const bf16x8*)((const char*)T[0] + off);
        al[mi] = *(const bf16x8*)((const char*)T[1] + off);
      }
#pragma unroll
      for (int ni = 0; ni < 2; ++ni){
        int row = wc*32 + ni*16 + l15;
        int off = row*128 + ((kk*64 + l16*16) ^ ((row & 7) << 4));
        bh[ni] = *(const bf16x8*)((const char*)T[2] + off);
        bl[ni] = *(const bf16x8*)((const char*)T[3] + off);
      }
#pragma unroll
      for (int mi = 0; mi < 4; ++mi)
#pragma unroll
        for (int ni = 0; ni < 2; ++ni){
          acc[mi][ni] = __builtin_amdgcn_mfma_f32_16x16x32_bf16(ah[mi], bh[ni], acc[mi][ni], 0, 0, 0);
          acc[mi][ni] = __builtin_amdgcn_mfma_f32_16x16x32_bf16(ah[mi], bl[ni], acc[mi][ni], 0, 0, 0);
          acc[mi][ni] = __builtin_amdgcn_mfma_f32_16x16x32_bf16(al[mi], bh[ni], acc[mi][ni], 0, 0, 0);
        }
    }
  }

#pragma unroll
  for (int mi = 0; mi < 4; ++mi)
#pragma unroll
    for (int ni = 0; ni < 2; ++ni){
      size_t gr = m0 + (size_t)(wr*64 + mi*16 + l16*4);
      size_t gc = n0 + (size_t)(wc*32 + ni*16 + l15);
#pragma unroll
      for (int v = 0; v < 4; ++v){
        float x = acc[mi][ni][v];
        Out[(gr + v) * (size_t)NN + gc] = 1.0f / (1.0f + __expf(-x));
      }
    }
}

extern "C" void kernel_launch(void* const* d_in, const int* in_sizes, int n_in,
                              void* d_out, int out_size, void* d_ws, size_t ws_size,
                              hipStream_t stream) {
  const float* X     = (const float*)d_in[0];
  const float* adj   = (const float*)d_in[1];
  const float* noise = (const float*)d_in[2];
  const float* W0    = (const float*)d_in[3];
  const float* Wmu   = (const float*)d_in[4];
  const float* Wls   = (const float*)d_in[5];
  float* out = (float*)d_out;
  char* ws = (char*)d_ws;

  unsigned short* XW0T = (unsigned short*)(ws);                 // 6291456 B
  unsigned short* HT   = (unsigned short*)(ws + 6291456);       // 6291456 B
  unsigned short* Zhi  = (unsigned short*)(ws + 12582912);      // 3145728 B
  unsigned short* Zlo  = (unsigned short*)(ws + 15728640);      // 3145728 B
  // split-K partials: [2][12288][256] f32 = 25165824 B; fall back to d_out (dead until decode)
  float* part = (ws_size >= (size_t)18874368 + 25165824)
              ? (float*)(ws + 18874368) : (float*)d_out;

  k_xw0<<<dim3(192, 8), 256, 0, stream>>>(X, W0, XW0T);
  k_gemm_adj<<<dim3(256, 2), 512, 0, stream>>>(adj, XW0T, part);
  k_combine_ht<<<dim3(192, 4), 256, 0, stream>>>(part, part + (size_t)NN * H1D, HT);
  k_gemm_adj<<<dim3(256, 2), 512, 0, stream>>>(adj, HT, part);
  k_heads<<<384, 256, 0, stream>>>(part, Wmu, Wls, noise, Zhi, Zlo);
  k_decode<<<dim3(96, 96), 512, 0, stream>>>(Zhi, Zlo, out);
}

// Round 4
// 718.834 us; speedup vs baseline: 1.1315x; 1.0060x over previous
//
#include <hip/hip_runtime.h>
#include <stdint.h>

#define NN 12288
#define IND 512
#define H1D 256
#define H2D 128

using bf16x8 = __attribute__((ext_vector_type(8))) short;
using f32x4  = __attribute__((ext_vector_type(4))) float;

__device__ __forceinline__ unsigned short f2bf(float f){
  unsigned int u = __float_as_uint(f);
  return (unsigned short)((u + 0x7fffu + ((u >> 16) & 1u)) >> 16);
}
__device__ __forceinline__ float bf2f(unsigned short h){
  return __uint_as_float(((unsigned int)h) << 16);
}
__device__ __forceinline__ void gload_lds16(const void* g, void* l){
  __builtin_amdgcn_global_load_lds(
      (const __attribute__((address_space(1))) unsigned int*)(uintptr_t)g,
      (__attribute__((address_space(3))) unsigned int*)(unsigned int)(uintptr_t)l,
      16, 0, 0);
}
__device__ __forceinline__ uint4 pack_bf8(f32x4 lo, f32x4 hi){
  uint4 pk;
  pk.x = (unsigned)f2bf(lo[0]) | ((unsigned)f2bf(lo[1]) << 16);
  pk.y = (unsigned)f2bf(lo[2]) | ((unsigned)f2bf(lo[3]) << 16);
  pk.z = (unsigned)f2bf(hi[0]) | ((unsigned)f2bf(hi[1]) << 16);
  pk.w = (unsigned)f2bf(hi[2]) | ((unsigned)f2bf(hi[3]) << 16);
  return pk;
}
__device__ __forceinline__ void step_sync(bool deep){
  if (deep) asm volatile("s_waitcnt vmcnt(2) lgkmcnt(0)" ::: "memory");
  else      asm volatile("s_waitcnt vmcnt(0) lgkmcnt(0)" ::: "memory");
  __builtin_amdgcn_s_barrier();
  __builtin_amdgcn_sched_barrier(0);
}

// ---------------- W0T[h][k] = bf16(W0[k][h]) ----------------
__global__ __launch_bounds__(256) void k_w0t(const float* __restrict__ W0,
                                             unsigned short* __restrict__ W0T){
  __shared__ float Ls[64][65];
  const int t = (int)threadIdx.x;
  const int k0 = (int)blockIdx.x * 64;
  const int h0 = (int)blockIdx.y * 64;
  {
    const int r = t >> 2, c = (t & 3) * 16;
    const float* p = W0 + (size_t)(k0 + r) * H1D + h0 + c;
#pragma unroll
    for (int q = 0; q < 4; ++q)
      *(float4*)&Ls[r][c + q*4] = *(const float4*)(p + q*4);
  }
  __syncthreads();
  const int h = t >> 2, kc = (t & 3) * 16;
  unsigned int pk[8];
#pragma unroll
  for (int q = 0; q < 8; ++q){
    float x0 = Ls[kc + q*2 + 0][h];
    float x1 = Ls[kc + q*2 + 1][h];
    pk[q] = (unsigned)f2bf(x0) | ((unsigned)f2bf(x1) << 16);
  }
  unsigned short* dst = W0T + (size_t)(h0 + h) * IND + k0 + kc;
  *(uint4*)(dst)     = *(uint4*)&pk[0];
  *(uint4*)(dst + 8) = *(uint4*)&pk[4];
}

// ------------- Unified pipelined GEMM: C[m0..m0+47, 0..255] = A[:, kslice] @ Bt[kslice]^T -------------
#define GEMM_MFMA(CUR) \
  { _Pragma("unroll") \
    for (int kk = 0; kk < 2; ++kk){ \
      bf16x8 af[3], bfr[2]; \
      _Pragma("unroll") \
      for (int mi = 0; mi < 3; ++mi){ \
        int row = mi*16 + l15; \
        int off = row*128 + ((kk*64 + l16*16) ^ ((row & 7) << 4)); \
        af[mi] = *(const bf16x8*)((const char*)Alds[CUR] + off); \
      } \
      _Pragma("unroll") \
      for (int ni = 0; ni < 2; ++ni){ \
        int row = w*32 + ni*16 + l15; \
        int off = row*128 + ((kk*64 + l16*16) ^ ((row & 7) << 4)); \
        bfr[ni] = *(const bf16x8*)((const char*)Blds[CUR] + off); \
      } \
      _Pragma("unroll") \
      for (int mi = 0; mi < 3; ++mi) \
        _Pragma("unroll") \
        for (int ni = 0; ni < 2; ++ni) \
          acc[mi][ni] = __builtin_amdgcn_mfma_f32_16x16x32_bf16(af[mi], bfr[ni], acc[mi][ni], 0, 0, 0); \
    } }

#define GLDS_B(SIDX, BUF) \
  { _Pragma("unroll") \
    for (int i = 0; i < 4; ++i){ \
      int P = i*8192 + t*16; \
      int row = P >> 7; \
      int Li = (P & 127) ^ ((row & 7) << 4); \
      gload_lds16(btb + (size_t)row * btsb + kbyte + (size_t)(SIDX)*128 + Li, \
                  (char*)Blds[BUF] + i*8192 + w*1024); \
    } }

template<int MODE, bool RELU>
__global__ __launch_bounds__(512, 4) void k_gemm(const float* __restrict__ A, int lda, int K,
                                                 const unsigned short* __restrict__ Bt, int bt_stride_e,
                                                 void* __restrict__ Out){
  __shared__ unsigned short Alds[2][48*64];
  __shared__ unsigned short Blds[2][256*64];
  const int t = (int)threadIdx.x;
  const int w = t >> 6, l = t & 63;
  const int l15 = l & 15, l16 = l >> 4;
  const int m0 = (int)blockIdx.x * 48;
  const int khalf = (int)blockIdx.y;
  const int kbase = khalf * K;
  const size_t kbyte = (size_t)kbase * 2;
  const size_t btsb = (size_t)bt_stride_e * 2;
  const char* btb = (const char*)Bt;
  const int S = K >> 6;

  f32x4 acc[3][2];
#pragma unroll
  for (int mi = 0; mi < 3; ++mi)
#pragma unroll
    for (int ni = 0; ni < 2; ++ni) acc[mi][ni] = 0;

  const int ar = t >> 3, ac8 = (t & 7) * 8;
  const bool astage = (t < 384);
  const float* abase = A + (size_t)(m0 + ar) * lda + kbase + ac8;
  const int aoff = ar*128 + ((ac8*2) ^ ((ar & 7) << 4));

  f32x4 a0l, a0h, a1l, a1h;
  if (astage){
    const f32x4* p0 = (const f32x4*)abase;
    a0l = __builtin_nontemporal_load(p0);
    a0h = __builtin_nontemporal_load(p0 + 1);
    const f32x4* p1 = (const f32x4*)(abase + 64);
    a1l = __builtin_nontemporal_load(p1);
    a1h = __builtin_nontemporal_load(p1 + 1);
  }
  GLDS_B(0, 0);
  if (astage) *(uint4*)((char*)Alds[0] + aoff) = pack_bf8(a0l, a0h);
  __syncthreads();

  for (int s = 0; s < S; s += 2){
    // ---- even step s (compute buf 0) ----
    if (s + 1 < S) GLDS_B(s + 1, 1);
    if (astage && s + 2 < S){
      const f32x4* p = (const f32x4*)(abase + (size_t)(s + 2) * 64);
      a0l = __builtin_nontemporal_load(p);
      a0h = __builtin_nontemporal_load(p + 1);
    }
    GEMM_MFMA(0);
    if (astage && s + 1 < S)
      *(uint4*)((char*)Alds[1] + aoff) = pack_bf8(a1l, a1h);
    if (s + 1 < S) step_sync(astage && (s + 2 < S));
    // ---- odd step s+1 (compute buf 1) ----
    if (s + 1 < S){
      if (s + 2 < S) GLDS_B(s + 2, 0);
      if (astage && s + 3 < S){
        const f32x4* p = (const f32x4*)(abase + (size_t)(s + 3) * 64);
        a1l = __builtin_nontemporal_load(p);
        a1h = __builtin_nontemporal_load(p + 1);
      }
      GEMM_MFMA(1);
      if (astage && s + 2 < S)
        *(uint4*)((char*)Alds[0] + aoff) = pack_bf8(a0l, a0h);
      if (s + 2 < S) step_sync(astage);
    }
  }

  if (MODE == 0){
    unsigned short* HT = (unsigned short*)Out;
#pragma unroll
    for (int mi = 0; mi < 3; ++mi)
#pragma unroll
      for (int ni = 0; ni < 2; ++ni){
        int gr = m0 + mi*16 + l16*4;
        int gc = w*32 + ni*16 + l15;
        float x0 = acc[mi][ni][0], x1 = acc[mi][ni][1];
        float x2 = acc[mi][ni][2], x3 = acc[mi][ni][3];
        if (RELU){ x0 = fmaxf(x0,0.f); x1 = fmaxf(x1,0.f); x2 = fmaxf(x2,0.f); x3 = fmaxf(x3,0.f); }
        uint2 pk;
        pk.x = (unsigned)f2bf(x0) | ((unsigned)f2bf(x1) << 16);
        pk.y = (unsigned)f2bf(x2) | ((unsigned)f2bf(x3) << 16);
        *(uint2*)(HT + (size_t)gc * NN + gr) = pk;
      }
  } else {
    float* P = (float*)Out + (size_t)khalf * NN * H1D;
#pragma unroll
    for (int mi = 0; mi < 3; ++mi)
#pragma unroll
      for (int ni = 0; ni < 2; ++ni){
        int gr = m0 + mi*16 + l16*4;
        int gc = w*32 + ni*16 + l15;
#pragma unroll
        for (int v = 0; v < 4; ++v)
          P[(size_t)(gr + v) * H1D + gc] = acc[mi][ni][v];
      }
  }
}

// ---------------- combine GEMM1 partials -> HT[h][n] = bf16(relu(p0+p1)) (transposed) ----------------
__global__ __launch_bounds__(256) void k_combine_ht(const float* __restrict__ p0,
                                                    const float* __restrict__ p1,
                                                    unsigned short* __restrict__ HT){
  __shared__ float Ls[64][65];
  const int t = (int)threadIdx.x;
  const int n0 = (int)blockIdx.x * 64;
  const int h0 = (int)blockIdx.y * 64;
  const int lr = t >> 4, lc = (t & 15) * 4;
#pragma unroll
  for (int q = 0; q < 4; ++q){
    int n = lr + q*16;
    size_t idx = (size_t)(n0 + n) * H1D + h0 + lc;
    float4 a = *(const float4*)(p0 + idx);
    float4 b = *(const float4*)(p1 + idx);
    Ls[n][lc+0] = fmaxf(a.x + b.x, 0.f);
    Ls[n][lc+1] = fmaxf(a.y + b.y, 0.f);
    Ls[n][lc+2] = fmaxf(a.z + b.z, 0.f);
    Ls[n][lc+3] = fmaxf(a.w + b.w, 0.f);
  }
  __syncthreads();
  const int hr = t >> 2, nc = (t & 3) * 16;
  unsigned int pk[8];
#pragma unroll
  for (int q = 0; q < 8; ++q){
    float x0 = Ls[nc + q*2 + 0][hr];
    float x1 = Ls[nc + q*2 + 1][hr];
    pk[q] = (unsigned)f2bf(x0) | ((unsigned)f2bf(x1) << 16);
  }
  unsigned short* dst = HT + (size_t)(h0 + hr) * NN + n0 + nc;
  *(uint4*)(dst)     = *(uint4*)&pk[0];
  *(uint4*)(dst + 8) = *(uint4*)&pk[4];
}

// ---------------- heads (sums GEMM2 partials) + reparam -> Zhi/Zlo ----------------
__global__ __launch_bounds__(256) void k_heads(const float* __restrict__ p0,
                                               const float* __restrict__ Wmu,
                                               const float* __restrict__ Wls,
                                               const float* __restrict__ noise,
                                               unsigned short* __restrict__ Zhi,
                                               unsigned short* __restrict__ Zlo){
  __shared__ float AHs[32][256];
  __shared__ float Wms[32][128];
  __shared__ float Wlss[32][128];
  const float* p1 = p0 + (size_t)NN * H1D;
  const int t  = (int)threadIdx.x;
  const int r0 = (int)blockIdx.x * 32;
  {
    const int r = t >> 3, c0 = (t & 7) * 32;
    size_t base = (size_t)(r0 + r) * H1D + c0;
#pragma unroll
    for (int q = 0; q < 8; ++q){
      float4 a = *(const float4*)(p0 + base + q*4);
      float4 b = *(const float4*)(p1 + base + q*4);
      AHs[r][c0 + q*4 + 0] = a.x + b.x;
      AHs[r][c0 + q*4 + 1] = a.y + b.y;
      AHs[r][c0 + q*4 + 2] = a.z + b.z;
      AHs[r][c0 + q*4 + 3] = a.w + b.w;
    }
  }
  const int j = t & 127, rg = t >> 7;
  float mu[16], ls[16];
#pragma unroll
  for (int r = 0; r < 16; ++r){ mu[r] = 0.f; ls[r] = 0.f; }

  for (int kc = 0; kc < 8; ++kc){
    __syncthreads();
    {
      const int r = t >> 3, c0 = (t & 7) * 16;
      const float* pm = Wmu + (size_t)(kc*32 + r) * H2D + c0;
      const float* pl = Wls + (size_t)(kc*32 + r) * H2D + c0;
#pragma unroll
      for (int q = 0; q < 4; ++q){
        *(float4*)&Wms[r][c0 + q*4]  = *(const float4*)(pm + q*4);
        *(float4*)&Wlss[r][c0 + q*4] = *(const float4*)(pl + q*4);
      }
    }
    __syncthreads();
#pragma unroll 4
    for (int k = 0; k < 32; ++k){
      float wm = Wms[k][j], wl = Wlss[k][j];
#pragma unroll
      for (int r = 0; r < 16; ++r){
        float a = AHs[rg*16 + r][kc*32 + k];
        mu[r] += a * wm;
        ls[r] += a * wl;
      }
    }
  }
#pragma unroll
  for (int r = 0; r < 16; ++r){
    const int i = r0 + rg*16 + r;
    float z = noise[(size_t)i * H2D + j] * __expf(ls[r]) + mu[r];
    unsigned short zh = f2bf(z);
    unsigned short zl = f2bf(z - bf2f(zh));
    Zhi[(size_t)i * H2D + j] = zh;
    Zlo[(size_t)i * H2D + j] = zl;
  }
}

// ---------------- decode: A_pred = sigmoid(Z @ Z^T), split-bf16 ----------------
__global__ __launch_bounds__(512) void k_decode(const unsigned short* __restrict__ Zhi,
                                                const unsigned short* __restrict__ Zlo,
                                                float* __restrict__ Out){
  __shared__ unsigned short T[4][128*64];
  const int t = (int)threadIdx.x;
  const int w = t >> 6, l = t & 63;
  const int l15 = l & 15, l16 = l >> 4;
  const int wr = w >> 2, wc = w & 3;
  const size_t m0 = (size_t)blockIdx.x * 128;
  const size_t n0 = (size_t)blockIdx.y * 128;

  f32x4 acc[4][2];
#pragma unroll
  for (int mi = 0; mi < 4; ++mi)
#pragma unroll
    for (int ni = 0; ni < 2; ++ni) acc[mi][ni] = 0;

#pragma unroll
  for (int p = 0; p < 2; ++p){
    if (p) __syncthreads();
#pragma unroll
    for (int i = 0; i < 2; ++i){
      int P = i*8192 + t*16;
      int row = P >> 7;
      int Li = (P & 127) ^ ((row & 7) << 4);
      size_t ga = (size_t)row * 256 + (size_t)p * 128 + Li;
      char* lb0 = (char*)T[0] + i*8192 + w*1024;
      char* lb1 = (char*)T[1] + i*8192 + w*1024;
      char* lb2 = (char*)T[2] + i*8192 + w*1024;
      char* lb3 = (char*)T[3] + i*8192 + w*1024;
      gload_lds16((const char*)Zhi + m0*256 + ga, lb0);
      gload_lds16((const char*)Zlo + m0*256 + ga, lb1);
      gload_lds16((const char*)Zhi + n0*256 + ga, lb2);
      gload_lds16((const char*)Zlo + n0*256 + ga, lb3);
    }
    __syncthreads();
#pragma unroll
    for (int kk = 0; kk < 2; ++kk){
      bf16x8 ah[4], al[4], bh[2], bl[2];
#pragma unroll
      for (int mi = 0; mi < 4; ++mi){
        int row = wr*64 + mi*16 + l15;
        int off = row*128 + ((kk*64 + l16*16) ^ ((row & 7) << 4));
        ah[mi] = *(const bf16x8*)((const char*)T[0] + off);
        al[mi] = *(const bf16x8*)((const char*)T[1] + off);
      }
#pragma unroll
      for (int ni = 0; ni < 2; ++ni){
        int row = wc*32 + ni*16 + l15;
        int off = row*128 + ((kk*64 + l16*16) ^ ((row & 7) << 4));
        bh[ni] = *(const bf16x8*)((const char*)T[2] + off);
        bl[ni] = *(const bf16x8*)((const char*)T[3] + off);
      }
#pragma unroll
      for (int mi = 0; mi < 4; ++mi)
#pragma unroll
        for (int ni = 0; ni < 2; ++ni){
          acc[mi][ni] = __builtin_amdgcn_mfma_f32_16x16x32_bf16(ah[mi], bh[ni], acc[mi][ni], 0, 0, 0);
          acc[mi][ni] = __builtin_amdgcn_mfma_f32_16x16x32_bf16(ah[mi], bl[ni], acc[mi][ni], 0, 0, 0);
          acc[mi][ni] = __builtin_amdgcn_mfma_f32_16x16x32_bf16(al[mi], bh[ni], acc[mi][ni], 0, 0, 0);
        }
    }
  }

#pragma unroll
  for (int mi = 0; mi < 4; ++mi)
#pragma unroll
    for (int ni = 0; ni < 2; ++ni){
      size_t gr = m0 + (size_t)(wr*64 + mi*16 + l16*4);
      size_t gc = n0 + (size_t)(wc*32 + ni*16 + l15);
#pragma unroll
      for (int v = 0; v < 4; ++v){
        float x = acc[mi][ni][v];
        float sg = 1.0f / (1.0f + __expf(-x));
        __builtin_nontemporal_store(sg, &Out[(gr + v) * (size_t)NN + gc]);
      }
    }
}

extern "C" void kernel_launch(void* const* d_in, const int* in_sizes, int n_in,
                              void* d_out, int out_size, void* d_ws, size_t ws_size,
                              hipStream_t stream) {
  const float* X     = (const float*)d_in[0];
  const float* adj   = (const float*)d_in[1];
  const float* noise = (const float*)d_in[2];
  const float* W0    = (const float*)d_in[3];
  const float* Wmu   = (const float*)d_in[4];
  const float* Wls   = (const float*)d_in[5];
  float* out = (float*)d_out;
  char* ws = (char*)d_ws;

  unsigned short* XW0T = (unsigned short*)(ws);                 // 6291456 B
  unsigned short* HT   = (unsigned short*)(ws + 6291456);       // 6291456 B
  unsigned short* Zhi  = (unsigned short*)(ws + 12582912);      // 3145728 B
  unsigned short* Zlo  = (unsigned short*)(ws + 15728640);      // 3145728 B
  unsigned short* W0T  = (unsigned short*)(ws + 18874368);      // 262144 B
  float* part = (ws_size >= (size_t)19136512 + 25165824)
              ? (float*)(ws + 19136512) : (float*)d_out;

  k_w0t<<<dim3(8, 4), 256, 0, stream>>>(W0, W0T);
  k_gemm<0,false><<<dim3(256, 1), 512, 0, stream>>>(X, IND, IND, W0T, IND, (void*)XW0T);
  k_gemm<1,false><<<dim3(256, 2), 512, 0, stream>>>(adj, NN, 6144, XW0T, NN, (void*)part);
  k_combine_ht<<<dim3(192, 4), 256, 0, stream>>>(part, part + (size_t)NN * H1D, HT);
  k_gemm<1,false><<<dim3(256, 2), 512, 0, stream>>>(adj, NN, 6144, HT, NN, (void*)part);
  k_heads<<<384, 256, 0, stream>>>(part, Wmu, Wls, noise, Zhi, Zlo);
  k_decode<<<dim3(96, 96), 512, 0, stream>>>(Zhi, Zlo, out);
}

// Round 6
// 627.728 us; speedup vs baseline: 1.2957x; 1.1451x over previous
//
#include <hip/hip_runtime.h>
#include <hip/hip_fp8.h>
#include <stdint.h>

#define NN 12288
#define IND 512
#define H1D 256
#define H2D 128

using bf16x8 = __attribute__((ext_vector_type(8))) short;
using f32x4  = __attribute__((ext_vector_type(4))) float;
using u32x4  = __attribute__((ext_vector_type(4))) unsigned int;

__device__ __forceinline__ unsigned short f2bf(float f){
  unsigned int u = __float_as_uint(f);
  return (unsigned short)((u + 0x7fffu + ((u >> 16) & 1u)) >> 16);
}
__device__ __forceinline__ float bf2f(unsigned short h){
  return __uint_as_float(((unsigned int)h) << 16);
}
__device__ __forceinline__ void gload_lds16(const void* g, void* l){
  __builtin_amdgcn_global_load_lds(
      (const __attribute__((address_space(1))) unsigned int*)(uintptr_t)g,
      (__attribute__((address_space(3))) unsigned int*)(unsigned int)(uintptr_t)l,
      16, 0, 0);
}
// pack two floats as e4m3 into low/high half of a 32-bit word (HI = word select, constexpr)
template<bool HI>
__device__ __forceinline__ unsigned cvt2(float a, float b, unsigned old){
#if __has_builtin(__builtin_amdgcn_cvt_pk_fp8_f32)
  return (unsigned)__builtin_amdgcn_cvt_pk_fp8_f32(a, b, (int)old, HI);
#else
  __hip_fp8_e4m3 pa(a), pb(b);
  unsigned v = (unsigned)pa.__x | ((unsigned)pb.__x << 8);
  return HI ? ((old & 0x0000FFFFu) | (v << 16)) : ((old & 0xFFFF0000u) | v);
#endif
}
__device__ __forceinline__ void sync_v(int n){
  switch(n){
    case 0: asm volatile("s_waitcnt vmcnt(0) lgkmcnt(0)" ::: "memory"); break;
    case 1: asm volatile("s_waitcnt vmcnt(1) lgkmcnt(0)" ::: "memory"); break;
    case 4: asm volatile("s_waitcnt vmcnt(4) lgkmcnt(0)" ::: "memory"); break;
    default: asm volatile("s_waitcnt vmcnt(5) lgkmcnt(0)" ::: "memory"); break;
  }
  __builtin_amdgcn_s_barrier();
  __builtin_amdgcn_sched_barrier(0);
}

// ---------------- W0T[h][k] = fp8(W0[k][h]) ----------------
__global__ __launch_bounds__(256) void k_w0t(const float* __restrict__ W0,
                                             char* __restrict__ W0T){
  __shared__ float Ls[64][65];
  const int t = (int)threadIdx.x;
  const int k0 = (int)blockIdx.x * 64;
  const int h0 = (int)blockIdx.y * 64;
  {
    const int r = t >> 2, c = (t & 3) * 16;
    const float* p = W0 + (size_t)(k0 + r) * H1D + h0 + c;
#pragma unroll
    for (int q = 0; q < 4; ++q)
      *(float4*)&Ls[r][c + q*4] = *(const float4*)(p + q*4);
  }
  __syncthreads();
  const int h = t >> 2, kc = (t & 3) * 16;
  u32x4 pk;
#pragma unroll
  for (int q = 0; q < 4; ++q){
    unsigned wv = cvt2<false>(Ls[kc+q*4+0][h], Ls[kc+q*4+1][h], 0u);
    wv = cvt2<true>(Ls[kc+q*4+2][h], Ls[kc+q*4+3][h], wv);
    pk[q] = wv;
  }
  *(u32x4*)(W0T + (size_t)(h0 + h) * IND + k0 + kc) = pk;
}

// ------------- fp8 pipelined GEMM: C[m0..m0+47, 0..255] = A[:,kslice] @ Bt[kslice]^T -------------
// AMODE 0: A f32 (scale folded into fp8 convert), optional DUMP of fp8 A.
// AMODE 1: A fp8 direct (pre-swizzled global_load_lds).
// MODE 0: fp8 store transposed into Out[256][NN]; MODE 1: f32 partials Out[khalf][NN][256].
#define GEMM_MFMA_F8(CUR) \
  { _Pragma("unroll") \
    for (int kk = 0; kk < 4; ++kk){ \
      long af[3]; long bfr[2]; \
      _Pragma("unroll") \
      for (int mi = 0; mi < 3; ++mi){ \
        int row = mi*16 + l15; \
        int off = row*128 + ((kk*32 + l16*8) ^ ((row & 7) << 4)); \
        af[mi] = *(const long*)(Alds[CUR] + off); \
      } \
      _Pragma("unroll") \
      for (int ni = 0; ni < 2; ++ni){ \
        int row = w*32 + ni*16 + l15; \
        int off = row*128 + ((kk*32 + l16*8) ^ ((row & 7) << 4)); \
        bfr[ni] = *(const long*)(Blds[CUR] + off); \
      } \
      _Pragma("unroll") \
      for (int mi = 0; mi < 3; ++mi) \
        _Pragma("unroll") \
        for (int ni = 0; ni < 2; ++ni) \
          acc[mi][ni] = __builtin_amdgcn_mfma_f32_16x16x32_fp8_fp8(af[mi], bfr[ni], acc[mi][ni], 0, 0, 0); \
    } }

#define GLDS_B(SIDX, BUF) \
  { _Pragma("unroll") \
    for (int i = 0; i < 4; ++i){ \
      int P = i*8192 + t*16; \
      int row = P >> 7; \
      int Li = (P & 127) ^ ((row & 7) << 4); \
      gload_lds16(btb + (size_t)row * btsb + kbB + (size_t)(SIDX)*128 + Li, \
                  Blds[BUF] + i*8192 + w*1024); \
    } }

#define GLDS_A(SIDX, BUF) \
  if (w < 6){ \
    gload_lds16(af8 + (size_t)(m0 + w*8 + rw8) * NN + kbase + (size_t)(SIDX)*128 + gsw, \
                Alds[BUF] + w*1024); \
  }

#define LOAD_A(Q0,Q1,Q2,Q3, SIDX) { \
  const float* p = abase + (size_t)(SIDX)*128; \
  Q0 = __builtin_nontemporal_load((const f32x4*)(p)); \
  Q1 = __builtin_nontemporal_load((const f32x4*)(p+4)); \
  Q2 = __builtin_nontemporal_load((const f32x4*)(p+8)); \
  Q3 = __builtin_nontemporal_load((const f32x4*)(p+12)); \
}

#define PACK_A(Q0,Q1,Q2,Q3, BUF, SIDX) { \
  u32x4 pk; \
  pk[0] = cvt2<false>(Q0[0]*ascale, Q0[1]*ascale, 0u); pk[0] = cvt2<true>(Q0[2]*ascale, Q0[3]*ascale, pk[0]); \
  pk[1] = cvt2<false>(Q1[0]*ascale, Q1[1]*ascale, 0u); pk[1] = cvt2<true>(Q1[2]*ascale, Q1[3]*ascale, pk[1]); \
  pk[2] = cvt2<false>(Q2[0]*ascale, Q2[1]*ascale, 0u); pk[2] = cvt2<true>(Q2[2]*ascale, Q2[3]*ascale, pk[2]); \
  pk[3] = cvt2<false>(Q3[0]*ascale, Q3[1]*ascale, 0u); pk[3] = cvt2<true>(Q3[2]*ascale, Q3[3]*ascale, pk[3]); \
  *(u32x4*)(Alds[BUF] + aoff) = pk; \
  if (DUMP) __builtin_nontemporal_store(pk, (u32x4*)(dumpP + (size_t)(m0 + ar) * NN + kbase + (size_t)(SIDX)*128 + ac)); \
}

template<int AMODE, int MODE, int DUMP>
__global__ __launch_bounds__(512, 4) void k_gemm_f8(const void* __restrict__ Ain, int lda, int K,
                                                    const char* __restrict__ Bt, int bt_stride_b,
                                                    float ascale, char* __restrict__ dumpP,
                                                    void* __restrict__ Out){
  __shared__ __align__(16) char Alds[2][48*128];
  __shared__ __align__(16) char Blds[2][256*128];
  const int t = (int)threadIdx.x;
  const int w = t >> 6, l = t & 63;
  const int l15 = l & 15, l16 = l >> 4;

  int midx, khalf;
  if (gridDim.x == 512){           // XCD-grouped remap: XCDs 0-3 -> khalf 0, 4-7 -> khalf 1
    int f = (int)blockIdx.x;
    int x = f & 7;
    khalf = x >> 2;
    midx = (f >> 3) * 4 + (x & 3);
  } else { khalf = 0; midx = (int)blockIdx.x; }
  const int m0 = midx * 48;
  const int kbase = khalf * K;       // elements (AMODE0) == bytes (fp8)
  const size_t kbB = (size_t)kbase;  // B offset bytes (fp8)
  const size_t btsb = (size_t)bt_stride_b;
  const char* btb = Bt;
  const int S = K >> 7;

  f32x4 acc[3][2];
#pragma unroll
  for (int mi = 0; mi < 3; ++mi)
#pragma unroll
    for (int ni = 0; ni < 2; ++ni) acc[mi][ni] = 0;

  // AMODE0 staging geometry
  const int ar = t >> 3, ac = (t & 7) * 16;
  const bool astage = (w < 6);
  const float* abase = (const float*)Ain + (size_t)(m0 + ar) * lda + kbase + ac;
  const int aoff = ar*128 + (ac ^ ((ar & 7) << 4));
  // AMODE1 staging geometry
  const char* af8 = (const char*)Ain;
  const int rw8 = l >> 3;
  const int gsw = ((l & 7) ^ rw8) << 4;

  if (AMODE == 0){
    f32x4 s0q0, s0q1, s0q2, s0q3, s1q0, s1q1, s1q2, s1q3;
    GLDS_B(0, 0);
    if (astage){
      LOAD_A(s0q0,s0q1,s0q2,s0q3, 0);
      if (S > 1) LOAD_A(s1q0,s1q1,s1q2,s1q3, 1);
      PACK_A(s0q0,s0q1,s0q2,s0q3, 0, 0);
    }
    sync_v(astage ? (DUMP ? 5 : 4) : 0);

    for (int s = 0; s < S; s += 2){
      // even step s: compute buf0
      if (s + 1 < S) GLDS_B(s + 1, 1);
      if (astage && s + 2 < S) LOAD_A(s0q0,s0q1,s0q2,s0q3, s + 2);
      GEMM_MFMA_F8(0);
      if (astage && s + 1 < S) PACK_A(s1q0,s1q1,s1q2,s1q3, 1, s + 1);
      if (s + 1 < S)
        sync_v(astage ? ((s + 2 < S) ? (DUMP ? 5 : 4) : (DUMP ? 1 : 0)) : 0);
      // odd step s+1: compute buf1
      if (s + 1 < S){
        if (s + 2 < S) GLDS_B(s + 2, 0);
        if (astage && s + 3 < S) LOAD_A(s1q0,s1q1,s1q2,s1q3, s + 3);
        GEMM_MFMA_F8(1);
        if (astage && s + 2 < S) PACK_A(s0q0,s0q1,s0q2,s0q3, 0, s + 2);
        if (s + 2 < S)
          sync_v(astage ? ((s + 3 < S) ? (DUMP ? 5 : 4) : (DUMP ? 1 : 0)) : 0);
      }
    }
  } else {
    GLDS_B(0, 0);
    GLDS_A(0, 0);
    sync_v(0);
    for (int s = 0; s < S; ++s){
      const int cur = s & 1, nxt = cur ^ 1;
      if (s + 1 < S){ GLDS_B(s + 1, nxt); GLDS_A(s + 1, nxt); }
      if (cur == 0){ GEMM_MFMA_F8(0); } else { GEMM_MFMA_F8(1); }
      if (s + 1 < S) sync_v(0);
    }
  }

  if (MODE == 0){
    char* OutT = (char*)Out;
#pragma unroll
    for (int mi = 0; mi < 3; ++mi)
#pragma unroll
      for (int ni = 0; ni < 2; ++ni){
        int gr = m0 + mi*16 + l16*4;
        int gc = w*32 + ni*16 + l15;
        unsigned wd = cvt2<false>(acc[mi][ni][0], acc[mi][ni][1], 0u);
        wd = cvt2<true>(acc[mi][ni][2], acc[mi][ni][3], wd);
        *(unsigned*)(OutT + (size_t)gc * NN + gr) = wd;
      }
  } else {
    float* P = (float*)Out + (size_t)khalf * NN * H1D;
#pragma unroll
    for (int mi = 0; mi < 3; ++mi)
#pragma unroll
      for (int ni = 0; ni < 2; ++ni){
        int gr = m0 + mi*16 + l16*4;
        int gc = w*32 + ni*16 + l15;
#pragma unroll
        for (int v = 0; v < 4; ++v)
          P[(size_t)(gr + v) * H1D + gc] = acc[mi][ni][v];
      }
  }
}

// ---------------- combine GEMM2 partials -> HidT[h][n] = fp8(relu(p0+p1)) (transposed) ----------------
__global__ __launch_bounds__(256) void k_combine_ht(const float* __restrict__ p0,
                                                    const float* __restrict__ p1,
                                                    char* __restrict__ HT){
  __shared__ float Ls[64][65];
  const int t = (int)threadIdx.x;
  const int n0 = (int)blockIdx.x * 64;
  const int h0 = (int)blockIdx.y * 64;
  const int lr = t >> 4, lc = (t & 15) * 4;
#pragma unroll
  for (int q = 0; q < 4; ++q){
    int n = lr + q*16;
    size_t idx = (size_t)(n0 + n) * H1D + h0 + lc;
    float4 a = *(const float4*)(p0 + idx);
    float4 b = *(const float4*)(p1 + idx);
    Ls[n][lc+0] = fmaxf(a.x + b.x, 0.f);
    Ls[n][lc+1] = fmaxf(a.y + b.y, 0.f);
    Ls[n][lc+2] = fmaxf(a.z + b.z, 0.f);
    Ls[n][lc+3] = fmaxf(a.w + b.w, 0.f);
  }
  __syncthreads();
  const int hr = t >> 2, nc = (t & 3) * 16;
  u32x4 pk;
#pragma unroll
  for (int q = 0; q < 4; ++q){
    unsigned wd = cvt2<false>(Ls[nc+q*4+0][hr], Ls[nc+q*4+1][hr], 0u);
    wd = cvt2<true>(Ls[nc+q*4+2][hr], Ls[nc+q*4+3][hr], wd);
    pk[q] = wd;
  }
  *(u32x4*)(HT + (size_t)(h0 + hr) * NN + n0 + nc) = pk;
}

// ---------------- heads (sums GEMM3 partials, x 2^-26) + reparam -> Zhi/Zlo ----------------
__global__ __launch_bounds__(256) void k_heads(const float* __restrict__ p0,
                                               const float* __restrict__ Wmu,
                                               const float* __restrict__ Wls,
                                               const float* __restrict__ noise,
                                               unsigned short* __restrict__ Zhi,
                                               unsigned short* __restrict__ Zlo){
  __shared__ float AHs[32][256];
  __shared__ float Wms[32][128];
  __shared__ float Wlss[32][128];
  const float INV = 1.0f / 67108864.0f;   // 2^-26 (undo S^2, S=2^13)
  const float* p1 = p0 + (size_t)NN * H1D;
  const int t  = (int)threadIdx.x;
  const int r0 = (int)blockIdx.x * 32;
  {
    const int r = t >> 3, c0 = (t & 7) * 32;
    size_t base = (size_t)(r0 + r) * H1D + c0;
#pragma unroll
    for (int q = 0; q < 8; ++q){
      float4 a = *(const float4*)(p0 + base + q*4);
      float4 b = *(const float4*)(p1 + base + q*4);
      AHs[r][c0 + q*4 + 0] = (a.x + b.x) * INV;
      AHs[r][c0 + q*4 + 1] = (a.y + b.y) * INV;
      AHs[r][c0 + q*4 + 2] = (a.z + b.z) * INV;
      AHs[r][c0 + q*4 + 3] = (a.w + b.w) * INV;
    }
  }
  const int j = t & 127, rg = t >> 7;
  float mu[16], ls[16];
#pragma unroll
  for (int r = 0; r < 16; ++r){ mu[r] = 0.f; ls[r] = 0.f; }

  for (int kc = 0; kc < 8; ++kc){
    __syncthreads();
    {
      const int r = t >> 3, c0 = (t & 7) * 16;
      const float* pm = Wmu + (size_t)(kc*32 + r) * H2D + c0;
      const float* pl = Wls + (size_t)(kc*32 + r) * H2D + c0;
#pragma unroll
      for (int q = 0; q < 4; ++q){
        *(float4*)&Wms[r][c0 + q*4]  = *(const float4*)(pm + q*4);
        *(float4*)&Wlss[r][c0 + q*4] = *(const float4*)(pl + q*4);
      }
    }
    __syncthreads();
#pragma unroll 4
    for (int k = 0; k < 32; ++k){
      float wm = Wms[k][j], wl = Wlss[k][j];
#pragma unroll
      for (int r = 0; r < 16; ++r){
        float a = AHs[rg*16 + r][kc*32 + k];
        mu[r] += a * wm;
        ls[r] += a * wl;
      }
    }
  }
#pragma unroll
  for (int r = 0; r < 16; ++r){
    const int i = r0 + rg*16 + r;
    float z = noise[(size_t)i * H2D + j] * __expf(ls[r]) + mu[r];
    unsigned short zh = f2bf(z);
    unsigned short zl = f2bf(z - bf2f(zh));
    Zhi[(size_t)i * H2D + j] = zh;
    Zlo[(size_t)i * H2D + j] = zl;
  }
}

// ---------------- decode: A_pred = sigmoid(Z @ Z^T), split-bf16 (unchanged, verified) ----------------
__global__ __launch_bounds__(512) void k_decode(const unsigned short* __restrict__ Zhi,
                                                const unsigned short* __restrict__ Zlo,
                                                float* __restrict__ Out){
  __shared__ unsigned short T[4][128*64];
  const int t = (int)threadIdx.x;
  const int w = t >> 6, l = t & 63;
  const int l15 = l & 15, l16 = l >> 4;
  const int wr = w >> 2, wc = w & 3;
  const size_t m0 = (size_t)blockIdx.x * 128;
  const size_t n0 = (size_t)blockIdx.y * 128;

  f32x4 acc[4][2];
#pragma unroll
  for (int mi = 0; mi < 4; ++mi)
#pragma unroll
    for (int ni = 0; ni < 2; ++ni) acc[mi][ni] = 0;

#pragma unroll
  for (int p = 0; p < 2; ++p){
    if (p) __syncthreads();
#pragma unroll
    for (int i = 0; i < 2; ++i){
      int P = i*8192 + t*16;
      int row = P >> 7;
      int Li = (P & 127) ^ ((row & 7) << 4);
      size_t ga = (size_t)row * 256 + (size_t)p * 128 + Li;
      char* lb0 = (char*)T[0] + i*8192 + w*1024;
      char* lb1 = (char*)T[1] + i*8192 + w*1024;
      char* lb2 = (char*)T[2] + i*8192 + w*1024;
      char* lb3 = (char*)T[3] + i*8192 + w*1024;
      gload_lds16((const char*)Zhi + m0*256 + ga, lb0);
      gload_lds16((const char*)Zlo + m0*256 + ga, lb1);
      gload_lds16((const char*)Zhi + n0*256 + ga, lb2);
      gload_lds16((const char*)Zlo + n0*256 + ga, lb3);
    }
    __syncthreads();
#pragma unroll
    for (int kk = 0; kk < 2; ++kk){
      bf16x8 ah[4], al[4], bh[2], bl[2];
#pragma unroll
      for (int mi = 0; mi < 4; ++mi){
        int row = wr*64 + mi*16 + l15;
        int off = row*128 + ((kk*64 + l16*16) ^ ((row & 7) << 4));
        ah[mi] = *(const bf16x8*)((const char*)T[0] + off);
        al[mi] = *(const bf16x8*)((const char*)T[1] + off);
      }
#pragma unroll
      for (int ni = 0; ni < 2; ++ni){
        int row = wc*32 + ni*16 + l15;
        int off = row*128 + ((kk*64 + l16*16) ^ ((row & 7) << 4));
        bh[ni] = *(const bf16x8*)((const char*)T[2] + off);
        bl[ni] = *(const bf16x8*)((const char*)T[3] + off);
      }
#pragma unroll
      for (int mi = 0; mi < 4; ++mi)
#pragma unroll
        for (int ni = 0; ni < 2; ++ni){
          acc[mi][ni] = __builtin_amdgcn_mfma_f32_16x16x32_bf16(ah[mi], bh[ni], acc[mi][ni], 0, 0, 0);
          acc[mi][ni] = __builtin_amdgcn_mfma_f32_16x16x32_bf16(ah[mi], bl[ni], acc[mi][ni], 0, 0, 0);
          acc[mi][ni] = __builtin_amdgcn_mfma_f32_16x16x32_bf16(al[mi], bh[ni], acc[mi][ni], 0, 0, 0);
        }
    }
  }

#pragma unroll
  for (int mi = 0; mi < 4; ++mi)
#pragma unroll
    for (int ni = 0; ni < 2; ++ni){
      size_t gr = m0 + (size_t)(wr*64 + mi*16 + l16*4);
      size_t gc = n0 + (size_t)(wc*32 + ni*16 + l15);
#pragma unroll
      for (int v = 0; v < 4; ++v){
        float x = acc[mi][ni][v];
        float sg = 1.0f / (1.0f + __expf(-x));
        __builtin_nontemporal_store(sg, &Out[(gr + v) * (size_t)NN + gc]);
      }
    }
}

extern "C" void kernel_launch(void* const* d_in, const int* in_sizes, int n_in,
                              void* d_out, int out_size, void* d_ws, size_t ws_size,
                              hipStream_t stream) {
  const float* X     = (const float*)d_in[0];
  const float* adj   = (const float*)d_in[1];
  const float* noise = (const float*)d_in[2];
  const float* W0    = (const float*)d_in[3];
  const float* Wmu   = (const float*)d_in[4];
  const float* Wls   = (const float*)d_in[5];
  float* out = (float*)d_out;
  char* ws = (char*)d_ws;

  // small fp8/bf16 arrays in ws (ws >= 31 MB proven in R1)
  char*           XW0Tf8 = ws;                                  // 256*12288   = 3145728
  char*           HidTf8 = ws + 3145728;                        // 3145728
  char*           W0Tf8  = ws + 6291456;                        // 256*512    = 131072
  unsigned short* Zhi    = (unsigned short*)(ws + 6422528);     // 3145728
  unsigned short* Zlo    = (unsigned short*)(ws + 9568256);     // 3145728
  // big scratch lives in d_out (dead until decode): adj_fp8 151 MB + partials 25 MB
  char*  adjf8 = (char*)d_out;                                  // 150994944
  float* part  = (float*)((char*)d_out + 150994944);            // 2*12288*256*4 = 25165824

  const float S_ADJ = 8192.0f;   // 2^13; heads divides by 2^26

  k_w0t<<<dim3(8, 4), 256, 0, stream>>>(W0, W0Tf8);
  // XW0T = (X @ W0)^T, fp8
  k_gemm_f8<0,0,0><<<256, 512, 0, stream>>>((const void*)X, IND, IND, W0Tf8, IND, 1.0f, nullptr, (void*)XW0Tf8);
  // part = (S*adj) @ XW0, f32 partials; side-dump adj_fp8 = fp8(S*adj)
  k_gemm_f8<0,1,1><<<512, 512, 0, stream>>>((const void*)adj, NN, 6144, XW0Tf8, NN, S_ADJ, adjf8, (void*)part);
  // HidT = fp8(relu(p0+p1)) = fp8(S*hidden), transposed
  k_combine_ht<<<dim3(192, 4), 256, 0, stream>>>(part, part + (size_t)NN * H1D, HidTf8);
  // part = (S*adj) @ (S*hidden) = S^2 * AH
  k_gemm_f8<1,1,0><<<512, 512, 0, stream>>>((const void*)adjf8, NN, 6144, HidTf8, NN, 1.0f, nullptr, (void*)part);
  k_heads<<<384, 256, 0, stream>>>(part, Wmu, Wls, noise, Zhi, Zlo);
  k_decode<<<dim3(96, 96), 512, 0, stream>>>(Zhi, Zlo, out);
}

// Round 7
// 616.575 us; speedup vs baseline: 1.3192x; 1.0181x over previous
//
#include <hip/hip_runtime.h>
#include <hip/hip_fp8.h>
#include <stdint.h>

#define NN 12288
#define IND 512
#define H1D 256
#define H2D 128

using bf16x8 = __attribute__((ext_vector_type(8))) short;
using f32x4  = __attribute__((ext_vector_type(4))) float;
using u32x4  = __attribute__((ext_vector_type(4))) unsigned int;

__device__ __forceinline__ unsigned short f2bf(float f){
  unsigned int u = __float_as_uint(f);
  return (unsigned short)((u + 0x7fffu + ((u >> 16) & 1u)) >> 16);
}
__device__ __forceinline__ float bf2f(unsigned short h){
  return __uint_as_float(((unsigned int)h) << 16);
}
__device__ __forceinline__ void gload_lds16(const void* g, void* l){
  __builtin_amdgcn_global_load_lds(
      (const __attribute__((address_space(1))) unsigned int*)(uintptr_t)g,
      (__attribute__((address_space(3))) unsigned int*)(unsigned int)(uintptr_t)l,
      16, 0, 0);
}
template<bool HI>
__device__ __forceinline__ unsigned cvt2(float a, float b, unsigned old){
#if __has_builtin(__builtin_amdgcn_cvt_pk_fp8_f32)
  return (unsigned)__builtin_amdgcn_cvt_pk_fp8_f32(a, b, (int)old, HI);
#else
  __hip_fp8_e4m3 pa(a), pb(b);
  unsigned v = (unsigned)pa.__x | ((unsigned)pb.__x << 8);
  return HI ? ((old & 0x0000FFFFu) | (v << 16)) : ((old & 0xFFFF0000u) | v);
#endif
}
__device__ __forceinline__ void sync0(){
  asm volatile("s_waitcnt vmcnt(0) lgkmcnt(0)" ::: "memory");
  __builtin_amdgcn_s_barrier();
  __builtin_amdgcn_sched_barrier(0);
}

// ---------------- streaming convert: out_fp8 = fp8(in_f32 * scale), 16 elems/thread/iter ----------------
__global__ __launch_bounds__(256) void k_cvt(const float* __restrict__ in,
                                             char* __restrict__ out,
                                             float scale, long n16){
  const long stride = (long)gridDim.x * 256;
  for (long i = (long)blockIdx.x * 256 + threadIdx.x; i < n16; i += stride){
    const f32x4* p = (const f32x4*)(in + i * 16);
    f32x4 a = __builtin_nontemporal_load(p);
    f32x4 b = __builtin_nontemporal_load(p + 1);
    f32x4 c = __builtin_nontemporal_load(p + 2);
    f32x4 d = __builtin_nontemporal_load(p + 3);
    u32x4 pk;
    pk[0] = cvt2<false>(a[0]*scale, a[1]*scale, 0u); pk[0] = cvt2<true>(a[2]*scale, a[3]*scale, pk[0]);
    pk[1] = cvt2<false>(b[0]*scale, b[1]*scale, 0u); pk[1] = cvt2<true>(b[2]*scale, b[3]*scale, pk[1]);
    pk[2] = cvt2<false>(c[0]*scale, c[1]*scale, 0u); pk[2] = cvt2<true>(c[2]*scale, c[3]*scale, pk[2]);
    pk[3] = cvt2<false>(d[0]*scale, d[1]*scale, 0u); pk[3] = cvt2<true>(d[2]*scale, d[3]*scale, pk[3]);
    *(u32x4*)(out + i * 16) = pk;   // normal store: keep fp8 copy L3-resident
  }
}

// ---------------- W0T[h][k] = fp8(W0[k][h]) ----------------
__global__ __launch_bounds__(256) void k_w0t(const float* __restrict__ W0,
                                             char* __restrict__ W0T){
  __shared__ float Ls[64][65];
  const int t = (int)threadIdx.x;
  const int k0 = (int)blockIdx.x * 64;
  const int h0 = (int)blockIdx.y * 64;
  {
    const int r = t >> 2, c = (t & 3) * 16;
    const float* p = W0 + (size_t)(k0 + r) * H1D + h0 + c;
#pragma unroll
    for (int q = 0; q < 4; ++q)
      *(float4*)&Ls[r][c + q*4] = *(const float4*)(p + q*4);
  }
  __syncthreads();
  const int h = t >> 2, kc = (t & 3) * 16;
  u32x4 pk;
#pragma unroll
  for (int q = 0; q < 4; ++q){
    unsigned wv = cvt2<false>(Ls[kc+q*4+0][h], Ls[kc+q*4+1][h], 0u);
    wv = cvt2<true>(Ls[kc+q*4+2][h], Ls[kc+q*4+3][h], wv);
    pk[q] = wv;
  }
  *(u32x4*)(W0T + (size_t)(h0 + h) * IND + k0 + kc) = pk;
}

// ------------- uniform fp8 GEMM: C[m0..m0+63, nh*128..+127] = A[:,kslice] @ Bt[kslice]^T -------------
// A fp8 [M][lda]; Bt fp8 [256][ldb] (k-contiguous rows). 256 threads, BM=64, BN=128, BK=128.
// MODE 0: fp8 store transposed into Out[256][NN]; MODE 1: f32 partials Out[khalf][NN][256].
#define STAGE(BUF, SIDX) { \
  _Pragma("unroll") \
  for (int p = 0; p < 2; ++p) \
    gload_lds16(Ap + (size_t)(p*32) * lda + (size_t)(SIDX)*128, \
                Alds[BUF] + p*4096 + w*1024); \
  _Pragma("unroll") \
  for (int i = 0; i < 4; ++i) \
    gload_lds16(Bp + (size_t)(i*32) * ldb + (size_t)(SIDX)*128, \
                Blds[BUF] + i*4096 + w*1024); \
}

#define MF8(CUR) { \
  _Pragma("unroll") \
  for (int kk = 0; kk < 4; ++kk){ \
    long af[4]; long bfr[2]; \
    _Pragma("unroll") \
    for (int mi = 0; mi < 4; ++mi){ \
      int row = mi*16 + l15; \
      int off = row*128 + ((kk*32 + l16*8) ^ ((row & 7) << 4)); \
      af[mi] = *(const long*)(Alds[CUR] + off); \
    } \
    _Pragma("unroll") \
    for (int ni = 0; ni < 2; ++ni){ \
      int row = w*32 + ni*16 + l15; \
      int off = row*128 + ((kk*32 + l16*8) ^ ((row & 7) << 4)); \
      bfr[ni] = *(const long*)(Blds[CUR] + off); \
    } \
    _Pragma("unroll") \
    for (int mi = 0; mi < 4; ++mi) \
      _Pragma("unroll") \
      for (int ni = 0; ni < 2; ++ni) \
        acc[mi][ni] = __builtin_amdgcn_mfma_f32_16x16x32_fp8_fp8(af[mi], bfr[ni], acc[mi][ni], 0, 0, 0); \
  } }

template<int KSPLIT, int MODE>
__global__ __launch_bounds__(256, 3) void k_gf8(const char* __restrict__ A, int lda, int K,
                                                const char* __restrict__ Bt, int ldb,
                                                void* __restrict__ Out){
  __shared__ __align__(16) char Alds[2][64*128];
  __shared__ __align__(16) char Blds[2][128*128];
  const int t = (int)threadIdx.x;
  const int w = t >> 6, l = t & 63;
  const int l15 = l & 15, l16 = l >> 4;

  int khalf, idx;
  if (KSPLIT == 2){                 // XCDs 0-3 -> khalf 0, XCDs 4-7 -> khalf 1
    int f = (int)blockIdx.x, x = f & 7;
    khalf = x >> 2;
    idx = (f >> 3) * 4 + (x & 3);   // 0..383
  } else { khalf = 0; idx = (int)blockIdx.x; }
  const int m0 = (idx >> 1) * 64;
  const int nh = idx & 1;
  const size_t kb = (size_t)khalf * K;   // fp8: elements == bytes
  const int S = K >> 7;

  f32x4 acc[4][2];
#pragma unroll
  for (int mi = 0; mi < 4; ++mi)
#pragma unroll
    for (int ni = 0; ni < 2; ++ni) acc[mi][ni] = 0;

  // staging source pointers (T21: pre-swizzled global source, linear LDS dest)
  const int swz = ((l & 7) ^ (l >> 3)) << 4;
  const char* Ap = A  + (size_t)(m0 + w*8 + (l >> 3)) * lda + kb + swz;
  const char* Bp = Bt + (size_t)(nh*128 + w*8 + (l >> 3)) * ldb + kb + swz;

  STAGE(0, 0);
  sync0();
  for (int s = 0; s < S; ++s){
    const int cur = s & 1;
    if (s + 1 < S){ if (cur == 0){ STAGE(1, s + 1); } else { STAGE(0, s + 1); } }
    if (cur == 0){ MF8(0); } else { MF8(1); }
    if (s + 1 < S) sync0();
  }

  if (MODE == 0){
    char* OutT = (char*)Out;
#pragma unroll
    for (int mi = 0; mi < 4; ++mi)
#pragma unroll
      for (int ni = 0; ni < 2; ++ni){
        int gr = m0 + mi*16 + l16*4;
        int gc = nh*128 + w*32 + ni*16 + l15;
        unsigned wd = cvt2<false>(acc[mi][ni][0], acc[mi][ni][1], 0u);
        wd = cvt2<true>(acc[mi][ni][2], acc[mi][ni][3], wd);
        *(unsigned*)(OutT + (size_t)gc * NN + gr) = wd;
      }
  } else {
    float* P = (float*)Out + (size_t)khalf * NN * H1D;
#pragma unroll
    for (int mi = 0; mi < 4; ++mi)
#pragma unroll
      for (int ni = 0; ni < 2; ++ni){
        int gr = m0 + mi*16 + l16*4;
        int gc = nh*128 + w*32 + ni*16 + l15;
#pragma unroll
        for (int v = 0; v < 4; ++v)
          P[(size_t)(gr + v) * H1D + gc] = acc[mi][ni][v];
      }
  }
}

// ---------------- combine GEMM2 partials -> HidT[h][n] = fp8(relu(p0+p1)) (transposed) ----------------
__global__ __launch_bounds__(256) void k_combine_ht(const float* __restrict__ p0,
                                                    const float* __restrict__ p1,
                                                    char* __restrict__ HT){
  __shared__ float Ls[64][65];
  const int t = (int)threadIdx.x;
  const int n0 = (int)blockIdx.x * 64;
  const int h0 = (int)blockIdx.y * 64;
  const int lr = t >> 4, lc = (t & 15) * 4;
#pragma unroll
  for (int q = 0; q < 4; ++q){
    int n = lr + q*16;
    size_t idx = (size_t)(n0 + n) * H1D + h0 + lc;
    float4 a = *(const float4*)(p0 + idx);
    float4 b = *(const float4*)(p1 + idx);
    Ls[n][lc+0] = fmaxf(a.x + b.x, 0.f);
    Ls[n][lc+1] = fmaxf(a.y + b.y, 0.f);
    Ls[n][lc+2] = fmaxf(a.z + b.z, 0.f);
    Ls[n][lc+3] = fmaxf(a.w + b.w, 0.f);
  }
  __syncthreads();
  const int hr = t >> 2, nc = (t & 3) * 16;
  u32x4 pk;
#pragma unroll
  for (int q = 0; q < 4; ++q){
    unsigned wd = cvt2<false>(Ls[nc+q*4+0][hr], Ls[nc+q*4+1][hr], 0u);
    wd = cvt2<true>(Ls[nc+q*4+2][hr], Ls[nc+q*4+3][hr], wd);
    pk[q] = wd;
  }
  *(u32x4*)(HT + (size_t)(h0 + hr) * NN + n0 + nc) = pk;
}

// ---------------- heads (sums GEMM3 partials, x 2^-26) + reparam -> Zhi/Zlo ----------------
__global__ __launch_bounds__(256) void k_heads(const float* __restrict__ p0,
                                               const float* __restrict__ Wmu,
                                               const float* __restrict__ Wls,
                                               const float* __restrict__ noise,
                                               unsigned short* __restrict__ Zhi,
                                               unsigned short* __restrict__ Zlo){
  __shared__ float AHs[32][256];
  __shared__ float Wms[32][128];
  __shared__ float Wlss[32][128];
  const float INV = 1.0f / 67108864.0f;   // 2^-26 (undo S^2, S=2^13)
  const float* p1 = p0 + (size_t)NN * H1D;
  const int t  = (int)threadIdx.x;
  const int r0 = (int)blockIdx.x * 32;
  {
    const int r = t >> 3, c0 = (t & 7) * 32;
    size_t base = (size_t)(r0 + r) * H1D + c0;
#pragma unroll
    for (int q = 0; q < 8; ++q){
      float4 a = *(const float4*)(p0 + base + q*4);
      float4 b = *(const float4*)(p1 + base + q*4);
      AHs[r][c0 + q*4 + 0] = (a.x + b.x) * INV;
      AHs[r][c0 + q*4 + 1] = (a.y + b.y) * INV;
      AHs[r][c0 + q*4 + 2] = (a.z + b.z) * INV;
      AHs[r][c0 + q*4 + 3] = (a.w + b.w) * INV;
    }
  }
  const int j = t & 127, rg = t >> 7;
  float mu[16], ls[16];
#pragma unroll
  for (int r = 0; r < 16; ++r){ mu[r] = 0.f; ls[r] = 0.f; }

  for (int kc = 0; kc < 8; ++kc){
    __syncthreads();
    {
      const int r = t >> 3, c0 = (t & 7) * 16;
      const float* pm = Wmu + (size_t)(kc*32 + r) * H2D + c0;
      const float* pl = Wls + (size_t)(kc*32 + r) * H2D + c0;
#pragma unroll
      for (int q = 0; q < 4; ++q){
        *(float4*)&Wms[r][c0 + q*4]  = *(const float4*)(pm + q*4);
        *(float4*)&Wlss[r][c0 + q*4] = *(const float4*)(pl + q*4);
      }
    }
    __syncthreads();
#pragma unroll 4
    for (int k = 0; k < 32; ++k){
      float wm = Wms[k][j], wl = Wlss[k][j];
#pragma unroll
      for (int r = 0; r < 16; ++r){
        float a = AHs[rg*16 + r][kc*32 + k];
        mu[r] += a * wm;
        ls[r] += a * wl;
      }
    }
  }
#pragma unroll
  for (int r = 0; r < 16; ++r){
    const int i = r0 + rg*16 + r;
    float z = noise[(size_t)i * H2D + j] * __expf(ls[r]) + mu[r];
    unsigned short zh = f2bf(z);
    unsigned short zl = f2bf(z - bf2f(zh));
    Zhi[(size_t)i * H2D + j] = zh;
    Zlo[(size_t)i * H2D + j] = zl;
  }
}

// ---------------- decode: A_pred = sigmoid(Z @ Z^T), split-bf16 (unchanged, verified) ----------------
__global__ __launch_bounds__(512) void k_decode(const unsigned short* __restrict__ Zhi,
                                                const unsigned short* __restrict__ Zlo,
                                                float* __restrict__ Out){
  __shared__ unsigned short T[4][128*64];
  const int t = (int)threadIdx.x;
  const int w = t >> 6, l = t & 63;
  const int l15 = l & 15, l16 = l >> 4;
  const int wr = w >> 2, wc = w & 3;
  const size_t m0 = (size_t)blockIdx.x * 128;
  const size_t n0 = (size_t)blockIdx.y * 128;

  f32x4 acc[4][2];
#pragma unroll
  for (int mi = 0; mi < 4; ++mi)
#pragma unroll
    for (int ni = 0; ni < 2; ++ni) acc[mi][ni] = 0;

#pragma unroll
  for (int p = 0; p < 2; ++p){
    if (p) __syncthreads();
#pragma unroll
    for (int i = 0; i < 2; ++i){
      int P = i*8192 + t*16;
      int row = P >> 7;
      int Li = (P & 127) ^ ((row & 7) << 4);
      size_t ga = (size_t)row * 256 + (size_t)p * 128 + Li;
      char* lb0 = (char*)T[0] + i*8192 + w*1024;
      char* lb1 = (char*)T[1] + i*8192 + w*1024;
      char* lb2 = (char*)T[2] + i*8192 + w*1024;
      char* lb3 = (char*)T[3] + i*8192 + w*1024;
      gload_lds16((const char*)Zhi + m0*256 + ga, lb0);
      gload_lds16((const char*)Zlo + m0*256 + ga, lb1);
      gload_lds16((const char*)Zhi + n0*256 + ga, lb2);
      gload_lds16((const char*)Zlo + n0*256 + ga, lb3);
    }
    __syncthreads();
#pragma unroll
    for (int kk = 0; kk < 2; ++kk){
      bf16x8 ah[4], al[4], bh[2], bl[2];
#pragma unroll
      for (int mi = 0; mi < 4; ++mi){
        int row = wr*64 + mi*16 + l15;
        int off = row*128 + ((kk*64 + l16*16) ^ ((row & 7) << 4));
        ah[mi] = *(const bf16x8*)((const char*)T[0] + off);
        al[mi] = *(const bf16x8*)((const char*)T[1] + off);
      }
#pragma unroll
      for (int ni = 0; ni < 2; ++ni){
        int row = wc*32 + ni*16 + l15;
        int off = row*128 + ((kk*64 + l16*16) ^ ((row & 7) << 4));
        bh[ni] = *(const bf16x8*)((const char*)T[2] + off);
        bl[ni] = *(const bf16x8*)((const char*)T[3] + off);
      }
#pragma unroll
      for (int mi = 0; mi < 4; ++mi)
#pragma unroll
        for (int ni = 0; ni < 2; ++ni){
          acc[mi][ni] = __builtin_amdgcn_mfma_f32_16x16x32_bf16(ah[mi], bh[ni], acc[mi][ni], 0, 0, 0);
          acc[mi][ni] = __builtin_amdgcn_mfma_f32_16x16x32_bf16(ah[mi], bl[ni], acc[mi][ni], 0, 0, 0);
          acc[mi][ni] = __builtin_amdgcn_mfma_f32_16x16x32_bf16(al[mi], bh[ni], acc[mi][ni], 0, 0, 0);
        }
    }
  }

#pragma unroll
  for (int mi = 0; mi < 4; ++mi)
#pragma unroll
    for (int ni = 0; ni < 2; ++ni){
      size_t gr = m0 + (size_t)(wr*64 + mi*16 + l16*4);
      size_t gc = n0 + (size_t)(wc*32 + ni*16 + l15);
#pragma unroll
      for (int v = 0; v < 4; ++v){
        float x = acc[mi][ni][v];
        float sg = 1.0f / (1.0f + __expf(-x));
        __builtin_nontemporal_store(sg, &Out[(gr + v) * (size_t)NN + gc]);
      }
    }
}

extern "C" void kernel_launch(void* const* d_in, const int* in_sizes, int n_in,
                              void* d_out, int out_size, void* d_ws, size_t ws_size,
                              hipStream_t stream) {
  const float* X     = (const float*)d_in[0];
  const float* adj   = (const float*)d_in[1];
  const float* noise = (const float*)d_in[2];
  const float* W0    = (const float*)d_in[3];
  const float* Wmu   = (const float*)d_in[4];
  const float* Wls   = (const float*)d_in[5];
  float* out = (float*)d_out;
  char* ws = (char*)d_ws;

  // small arrays in ws (~18.2 MB total; ws proven >= ~19 MB)
  char*           XW0Tf8 = ws;                                  // 3145728
  char*           HidTf8 = ws + 3145728;                        // 3145728
  char*           W0Tf8  = ws + 6291456;                        // 131072
  unsigned short* Zhi    = (unsigned short*)(ws + 6422528);     // 3145728
  unsigned short* Zlo    = (unsigned short*)(ws + 9568256);     // 3145728
  char*           Xf8    = ws + 12713984;                       // 12288*512 = 6291456
  // big scratch in d_out (dead until decode): adj_fp8 151 MB + partials 25 MB
  char*  adjf8 = (char*)d_out;                                  // 150994944
  float* part  = (float*)((char*)d_out + 150994944);            // 25165824

  const float S_ADJ = 8192.0f;   // 2^13; heads divides by 2^26

  // adj -> fp8(S*adj) (streaming; fp8 copy stays L3-resident for both GEMMs)
  k_cvt<<<2048, 256, 0, stream>>>(adj, adjf8, S_ADJ, (long)NN * NN / 16);
  k_w0t<<<dim3(8, 4), 256, 0, stream>>>(W0, W0Tf8);
  k_cvt<<<256, 256, 0, stream>>>(X, Xf8, 1.0f, (long)NN * IND / 16);
  // XW0T = (X @ W0)^T, fp8
  k_gf8<1,0><<<384, 256, 0, stream>>>(Xf8, IND, IND, W0Tf8, IND, (void*)XW0Tf8);
  // part = fp8(S*adj) @ XW0, f32 partials
  k_gf8<2,1><<<768, 256, 0, stream>>>(adjf8, NN, 6144, XW0Tf8, NN, (void*)part);
  // HidT = fp8(relu(p0+p1)) = fp8(S*hidden), transposed
  k_combine_ht<<<dim3(192, 4), 256, 0, stream>>>(part, part + (size_t)NN * H1D, HidTf8);
  // part = fp8(S*adj) @ fp8(S*hidden) = S^2 * AH
  k_gf8<2,1><<<768, 256, 0, stream>>>(adjf8, NN, 6144, HidTf8, NN, (void*)part);
  k_heads<<<384, 256, 0, stream>>>(part, Wmu, Wls, noise, Zhi, Zlo);
  k_decode<<<dim3(96, 96), 512, 0, stream>>>(Zhi, Zlo, out);
}